// Round 5
// baseline (410.967 us; speedup 1.0000x reference)
//
#include <hip/hip_runtime.h>
#include <cstdint>
#include <cstddef>

constexpr int BLK = 256;

static inline size_t ws_align(size_t x) { return (x + 255) & ~size_t(255); }

typedef __attribute__((ext_vector_type(8))) short bf16x8;
typedef __attribute__((ext_vector_type(4))) float f32x4;

__device__ inline unsigned short f2bf(float f) {
  unsigned int u = __float_as_uint(f);
  unsigned int r = (u + 0x7fffu + ((u >> 16) & 1u)) >> 16;   // RNE
  return (unsigned short)r;
}
__device__ inline float bf2f(unsigned short u) {
  return __uint_as_float(((unsigned int)u) << 16);
}
__device__ inline float bf2f_lo(unsigned int w) {
  return __uint_as_float(w << 16);
}
__device__ inline float bf2f_hi(unsigned int w) {
  return __uint_as_float(w & 0xffff0000u);
}

// ---------------- edge layout detect & pack ----------------
__global__ void k_detect(const int* __restrict__ ei, int* __restrict__ flag) {
  int allz = 1;
  for (int i = 0; i < 32; ++i) allz &= (ei[2 * i + 1] == 0) ? 1 : 0;
  flag[0] = allz;
}

// pk[i] = (col << 16) | row   (N <= 65536)
__global__ void k_pack(const int* __restrict__ ei, const int* __restrict__ flag,
                       unsigned int* __restrict__ pk, int E) {
  int i = blockIdx.x * BLK + threadIdx.x;
  if (i >= E) return;
  int row, col;
  if (flag[0]) { row = ei[2 * i]; col = ei[2 * (E + i)]; }
  else         { row = ei[i];     col = ei[E + i]; }
  pk[i] = ((unsigned int)col << 16) | (unsigned int)row;
}

// ---------------- degree, dis, scan (CSR offsets) ----------------
__global__ void k_deg(const unsigned int* __restrict__ pk, int* __restrict__ deg, int E) {
  int i = blockIdx.x * BLK + threadIdx.x;
  if (i < E) atomicAdd(&deg[pk[i] >> 16], 1);
}

__global__ void k_dis(const int* __restrict__ deg, float* __restrict__ dis, int n) {
  int i = blockIdx.x * BLK + threadIdx.x;
  if (i < n) dis[i] = 1.0f / sqrtf((float)(deg[i] + 1));
}

__global__ void k_scan1(const int* __restrict__ deg, int* __restrict__ offs,
                        int* __restrict__ bsum, int n) {
  __shared__ int wsums[5];
  int i = blockIdx.x * BLK + threadIdx.x;
  int v = (i < n) ? deg[i] : 0;
  int lane = threadIdx.x & 63, w = threadIdx.x >> 6;
  int x = v;
  #pragma unroll
  for (int s = 1; s < 64; s <<= 1) { int t = __shfl_up(x, s); if (lane >= s) x += t; }
  if (lane == 63) wsums[w] = x;
  __syncthreads();
  if (threadIdx.x == 0) {
    int a = 0;
    for (int k = 0; k < 4; ++k) { int t = wsums[k]; wsums[k] = a; a += t; }
    wsums[4] = a;
  }
  __syncthreads();
  int incl = x + wsums[w];
  if (i < n) offs[i] = incl - v;
  if (threadIdx.x == 0) bsum[blockIdx.x] = wsums[4];
}

__global__ void k_scan2(int* __restrict__ bsum, int nb) {
  __shared__ int wsums[5];
  int v = (threadIdx.x < nb) ? bsum[threadIdx.x] : 0;
  int lane = threadIdx.x & 63, w = threadIdx.x >> 6;
  int x = v;
  #pragma unroll
  for (int s = 1; s < 64; s <<= 1) { int t = __shfl_up(x, s); if (lane >= s) x += t; }
  if (lane == 63) wsums[w] = x;
  __syncthreads();
  if (threadIdx.x == 0) {
    int a = 0;
    for (int k = 0; k < 4; ++k) { int t = wsums[k]; wsums[k] = a; a += t; }
    wsums[4] = a;
  }
  __syncthreads();
  int incl = x + wsums[w];
  if (threadIdx.x < nb) bsum[threadIdx.x] = incl - v;
}

__global__ void k_scan3(int* __restrict__ offs, const int* __restrict__ bsum,
                        int n, int E) {
  int i = blockIdx.x * BLK + threadIdx.x;
  if (i < n) offs[i] += bsum[i >> 8];
  if (i == 0) offs[n] = E;
}

// ---------------- XCD-affine scatter ----------------
// Block bIdx%8==c handles cols in [c*W, (c+1)*W): csr window ~E/8*4B fits one
// XCD L2 -> dirty lines combine and write back once (perf heuristic only).
__global__ void k_scatter_aff(const unsigned int* __restrict__ pk,
                              const int* __restrict__ offs, int* __restrict__ cursor,
                              int* __restrict__ csr, int E, int W, int nGroupBlocks) {
  const int c = blockIdx.x & 7;
  const int j = blockIdx.x >> 3;
  const unsigned int lo = (unsigned int)(c * W), hi = lo + (unsigned int)W;
  const int stride = nGroupBlocks * BLK;
  for (int i = j * BLK + threadIdx.x; i < E; i += stride) {
    unsigned int p = pk[i];
    unsigned int col = p >> 16;
    if (col >= lo && col < hi) {
      int pos = offs[col] + atomicAdd(&cursor[col], 1);
      csr[pos] = (int)(p & 0xffffu);
    }
  }
}

// ---------------- W (K x NOUT fp32) -> WT (NOUTP x K bf16, zero-padded) ----------------
template<int K, int NOUT, int NOUTP>
__global__ void k_wt(const float* __restrict__ W, unsigned short* __restrict__ WT) {
  int i = blockIdx.x * BLK + threadIdx.x;
  if (i >= NOUTP * K) return;
  int n = i / K, k = i % K;
  float v = (n < NOUT) ? W[(size_t)k * NOUT + n] : 0.f;
  WT[i] = f2bf(v);
}

// ---------------- MFMA GEMM: C[i][j] = (sum_k A[i][k]*W[k][j]) * (dis?dis[i]:1) ----------------
// A: [N][K] (fp32 if AF32 else bf16), row stride == K. WT: [NT*16][K] bf16 row-major.
// C: bf16, row stride ldc. Block = 4 waves; each wave computes (MR*16) x (NT*16).
template<int K, int NT, int MR, bool AF32>
__launch_bounds__(256)
__global__ void k_mgemm(const void* __restrict__ Av, const unsigned short* __restrict__ WT,
                        const float* __restrict__ dis, unsigned short* __restrict__ C,
                        int ldc, int NOUT, int N) {
  const int tid = threadIdx.x;
  const int lane = tid & 63;
  const int wv = tid >> 6;
  const int m = lane & 15;          // operand outer index
  const int kq = lane >> 4;         // 0..3 (k-quad)
  const int orow = blockIdx.x * (64 * MR) + wv * (16 * MR);

  int rowc[MR];
  #pragma unroll
  for (int mr = 0; mr < MR; ++mr) {
    int row = orow + mr * 16 + m;
    rowc[mr] = row < N ? row : N - 1;   // clamp loads; store is guarded
  }

  f32x4 acc[MR][NT];
  #pragma unroll
  for (int mr = 0; mr < MR; ++mr)
    #pragma unroll
    for (int t = 0; t < NT; ++t) acc[mr][t] = {0.f, 0.f, 0.f, 0.f};

  #pragma unroll 2
  for (int k0 = 0; k0 < K; k0 += 32) {
    bf16x8 af[MR];
    #pragma unroll
    for (int mr = 0; mr < MR; ++mr) {
      if constexpr (AF32) {
        const float* Arow = (const float*)Av + (size_t)rowc[mr] * K + kq * 8 + k0;
        float4 a0 = *(const float4*)Arow;
        float4 a1 = *(const float4*)(Arow + 4);
        af[mr][0] = (short)f2bf(a0.x); af[mr][1] = (short)f2bf(a0.y);
        af[mr][2] = (short)f2bf(a0.z); af[mr][3] = (short)f2bf(a0.w);
        af[mr][4] = (short)f2bf(a1.x); af[mr][5] = (short)f2bf(a1.y);
        af[mr][6] = (short)f2bf(a1.z); af[mr][7] = (short)f2bf(a1.w);
      } else {
        const unsigned short* Arow = (const unsigned short*)Av + (size_t)rowc[mr] * K + kq * 8 + k0;
        af[mr] = *(const bf16x8*)Arow;
      }
    }
    bf16x8 bf[NT];
    #pragma unroll
    for (int t = 0; t < NT; ++t)
      bf[t] = *(const bf16x8*)(WT + (size_t)(t * 16 + m) * K + k0 + kq * 8);
    #pragma unroll
    for (int t = 0; t < NT; ++t)
      #pragma unroll
      for (int mr = 0; mr < MR; ++mr)
        acc[mr][t] = __builtin_amdgcn_mfma_f32_16x16x32_bf16(af[mr], bf[t], acc[mr][t], 0, 0, 0);
  }
  // C/D layout: col = lane&15 (=m), row = kq*4 + r
  #pragma unroll
  for (int mr = 0; mr < MR; ++mr) {
    #pragma unroll
    for (int r = 0; r < 4; ++r) {
      int rr = orow + mr * 16 + kq * 4 + r;
      if (rr < N) {
        float s = dis ? dis[rr] : 1.f;
        #pragma unroll
        for (int t = 0; t < NT; ++t) {
          int cc = t * 16 + m;
          if (cc < NOUT)
            C[(size_t)rr * ldc + cc] = f2bf(acc[mr][t][r] * s);
        }
      }
    }
  }
}

// ---------------- aggregation: out[v] = dis[v]*(g[v] + sum_in g[u]) + b ----------------
// g is bf16 [N][ldg]. dst: bf16 (intermediate) or fp32 (final, with log-softmax).
template<int D, bool RELU, bool LOGSM, bool OUTF32>
__launch_bounds__(BLK)
__global__ void k_agg(const unsigned short* __restrict__ g, int ldg,
                      const float* __restrict__ dis, const float* __restrict__ bias,
                      const int* __restrict__ offs, const int* __restrict__ csr,
                      void* __restrict__ dstv, int ldd, int N) {
  int wid = (blockIdx.x * BLK + threadIdx.x) >> 6;
  int lane = threadIdx.x & 63;
  if (wid >= N) return;
  float acc0 = 0.f, acc1 = 0.f;
  if constexpr (D == 128) {
    unsigned int w = *(const unsigned int*)&g[(size_t)wid * ldg + lane * 2];
    acc0 = bf2f_lo(w); acc1 = bf2f_hi(w);
  } else {
    if (lane < D) acc0 = bf2f(g[(size_t)wid * ldg + lane]);
  }
  int beg = offs[wid], end = offs[wid + 1];
  for (int e0 = beg; e0 < end; e0 += 64) {
    int cnt = end - e0; if (cnt > 64) cnt = 64;
    int u = (lane < cnt) ? csr[e0 + lane] : 0;
    int j = 0;
    for (; j + 3 < cnt; j += 4) {
      int u0 = __shfl(u, j), u1 = __shfl(u, j + 1);
      int u2 = __shfl(u, j + 2), u3 = __shfl(u, j + 3);
      if constexpr (D == 128) {
        unsigned int w0 = *(const unsigned int*)&g[(size_t)u0 * ldg + lane * 2];
        unsigned int w1 = *(const unsigned int*)&g[(size_t)u1 * ldg + lane * 2];
        unsigned int w2 = *(const unsigned int*)&g[(size_t)u2 * ldg + lane * 2];
        unsigned int w3 = *(const unsigned int*)&g[(size_t)u3 * ldg + lane * 2];
        acc0 += bf2f_lo(w0) + bf2f_lo(w1) + bf2f_lo(w2) + bf2f_lo(w3);
        acc1 += bf2f_hi(w0) + bf2f_hi(w1) + bf2f_hi(w2) + bf2f_hi(w3);
      } else {
        if (lane < D) {
          float v0 = bf2f(g[(size_t)u0 * ldg + lane]);
          float v1 = bf2f(g[(size_t)u1 * ldg + lane]);
          float v2 = bf2f(g[(size_t)u2 * ldg + lane]);
          float v3 = bf2f(g[(size_t)u3 * ldg + lane]);
          acc0 += (v0 + v1) + (v2 + v3);
        }
      }
    }
    for (; j < cnt; ++j) {
      int u0 = __shfl(u, j);
      if constexpr (D == 128) {
        unsigned int w0 = *(const unsigned int*)&g[(size_t)u0 * ldg + lane * 2];
        acc0 += bf2f_lo(w0); acc1 += bf2f_hi(w0);
      } else {
        if (lane < D) acc0 += bf2f(g[(size_t)u0 * ldg + lane]);
      }
    }
  }
  float dv = dis[wid];
  if constexpr (D == 128) {
    float ox = dv * acc0 + bias[lane * 2];
    float oy = dv * acc1 + bias[lane * 2 + 1];
    if constexpr (RELU) { ox = fmaxf(ox, 0.f); oy = fmaxf(oy, 0.f); }
    unsigned int pw = (unsigned int)f2bf(ox) | ((unsigned int)f2bf(oy) << 16);
    *(unsigned int*)&((unsigned short*)dstv)[(size_t)wid * ldd + lane * 2] = pw;
  } else {
    float o = 0.f;
    if (lane < D) o = dv * acc0 + bias[lane];
    if constexpr (RELU) o = fmaxf(o, 0.f);
    if constexpr (LOGSM) {
      float v = (lane < D) ? o : -__builtin_inff();
      float mx = v;
      #pragma unroll
      for (int s = 32; s >= 1; s >>= 1) mx = fmaxf(mx, __shfl_xor(mx, s));
      float ex = (lane < D) ? expf(v - mx) : 0.f;
      float sum = ex;
      #pragma unroll
      for (int s = 32; s >= 1; s >>= 1) sum += __shfl_xor(sum, s);
      o = v - mx - logf(sum);
    }
    if (lane < D) {
      if constexpr (OUTF32) ((float*)dstv)[(size_t)wid * ldd + lane] = o;
      else ((unsigned short*)dstv)[(size_t)wid * ldd + lane] = f2bf(o);
    }
  }
}

// ---------------- launcher ----------------
extern "C" void kernel_launch(void* const* d_in, const int* in_sizes, int n_in,
                              void* d_out, int out_size, void* d_ws, size_t ws_size,
                              hipStream_t stream) {
  const float* x    = (const float*)d_in[0];
  const int*   ei   = (const int*)d_in[1];
  const float* eig  = (const float*)d_in[2];
  const float* W1   = (const float*)d_in[3];
  const float* b1   = (const float*)d_in[4];
  const float* W2   = (const float*)d_in[5];
  const float* b2   = (const float*)d_in[6];
  const float* linW = (const float*)d_in[7];
  const float* W3   = (const float*)d_in[8];
  const float* b3   = (const float*)d_in[9];
  float* out = (float*)d_out;

  const int N = in_sizes[0] / 512;
  const int E = in_sizes[1] / 2;

  char* ws = (char*)d_ws;
  size_t off = 0;
  auto alloc = [&](size_t bytes) { char* p = ws + off; off = ws_align(off + bytes); return p; };
  unsigned int* pk = (unsigned int*)alloc((size_t)E * 4);   // packed (col<<16)|row
  int*   csr    = (int*)alloc((size_t)E * 4);
  int*   deg    = (int*)alloc((size_t)N * 4);
  int*   offs   = (int*)alloc((size_t)(N + 1) * 4);
  int*   cursor = (int*)alloc((size_t)N * 4);
  int*   bsum   = (int*)alloc(4096);
  int*   flag   = (int*)alloc(256);
  float* dis    = (float*)alloc((size_t)N * 4);
  unsigned short* F = (unsigned short*)alloc((size_t)N * 128 * 2);  // conv GEMM outputs, bf16
  unsigned short* G = (unsigned short*)alloc((size_t)N * 128 * 2);  // h1 then hcat, bf16
  unsigned short* WT1 = (unsigned short*)alloc(128 * 512 * 2);
  unsigned short* WT2 = (unsigned short*)alloc(64 * 128 * 2);
  unsigned short* WTl = (unsigned short*)alloc(64 * 128 * 2);
  unsigned short* WT3 = (unsigned short*)alloc(48 * 128 * 2);

  hipMemsetAsync(deg, 0, (size_t)N * 4, stream);
  hipMemsetAsync(cursor, 0, (size_t)N * 4, stream);

  const int gE = (E + BLK - 1) / BLK;
  const int gN = (N + BLK - 1) / BLK;

  k_detect<<<1, 1, 0, stream>>>(ei, flag);
  k_pack<<<gE, BLK, 0, stream>>>(ei, flag, pk, E);
  k_deg<<<gE, BLK, 0, stream>>>(pk, deg, E);
  k_dis<<<gN, BLK, 0, stream>>>(deg, dis, N);
  k_scan1<<<gN, BLK, 0, stream>>>(deg, offs, bsum, N);
  k_scan2<<<1, BLK, 0, stream>>>(bsum, gN);
  k_scan3<<<gN, BLK, 0, stream>>>(offs, bsum, N, E);
  const int W8 = (N + 7) / 8;               // node window per XCD group
  const int nGroupBlocks = 64;              // 8 * 64 = 512 blocks
  k_scatter_aff<<<8 * nGroupBlocks, BLK, 0, stream>>>(pk, offs, cursor, csr, E, W8, nGroupBlocks);

  // weight conversions (tiny)
  k_wt<512, 128, 128><<<(128 * 512 + BLK - 1) / BLK, BLK, 0, stream>>>(W1, WT1);
  k_wt<128, 64, 64><<<(64 * 128 + BLK - 1) / BLK, BLK, 0, stream>>>(W2, WT2);
  k_wt<128, 64, 64><<<(64 * 128 + BLK - 1) / BLK, BLK, 0, stream>>>(linW, WTl);
  k_wt<128, 40, 48><<<(48 * 128 + BLK - 1) / BLK, BLK, 0, stream>>>(W3, WT3);

  const int gG2 = (N + 127) / 128;    // MFMA GEMM blocks (MR=2 -> 128 rows/block)
  const int gA = (N + 3) / 4;         // agg blocks (4 waves/block)

  // conv1: g1 = (x @ W1)*dis ; h1 = relu(dis*(g1[v]+sum) + b1)   [h1 -> G, bf16]
  k_mgemm<512, 8, 2, true><<<gG2, BLK, 0, stream>>>(x, WT1, dis, F, 128, 128, N);
  k_agg<128, true, false, false><<<gA, BLK, 0, stream>>>(F, 128, dis, b1, offs, csr, G, 128, N);
  // conv2: g2 = (h1 @ W2)*dis ; spectral xp = eig @ linW into right half of G
  k_mgemm<128, 4, 2, false><<<gG2, BLK, 0, stream>>>(G, WT2, dis, F, 64, 64, N);
  k_mgemm<128, 4, 2, true><<<gG2, BLK, 0, stream>>>(eig, WTl, nullptr, G + 64, 128, 64, N);
  k_agg<64, true, false, false><<<gA, BLK, 0, stream>>>(F, 64, dis, b2, offs, csr, G, 128, N);
  // conv3: g3 = (hcat @ W3)*dis ; out = log_softmax(dis*(g3[v]+sum)+b3)  [fp32 out]
  k_mgemm<128, 3, 2, false><<<gG2, BLK, 0, stream>>>(G, WT3, dis, F, 40, 40, N);
  k_agg<40, false, true, true><<<gA, BLK, 0, stream>>>(F, 40, dis, b3, offs, csr, out, 40, N);
}

// Round 6
// 394.789 us; speedup vs baseline: 1.0410x; 1.0410x over previous
//
#include <hip/hip_runtime.h>
#include <cstdint>
#include <cstddef>

constexpr int BLK = 256;
constexpr int NB = 128;          // partition blocks

static inline size_t ws_align(size_t x) { return (x + 255) & ~size_t(255); }

typedef __attribute__((ext_vector_type(8))) short bf16x8;
typedef __attribute__((ext_vector_type(4))) float f32x4;

__device__ inline unsigned short f2bf(float f) {
  unsigned int u = __float_as_uint(f);
  unsigned int r = (u + 0x7fffu + ((u >> 16) & 1u)) >> 16;   // RNE
  return (unsigned short)r;
}
__device__ inline float bf2f(unsigned short u) {
  return __uint_as_float(((unsigned int)u) << 16);
}
__device__ inline float bf2f_lo(unsigned int w) {
  return __uint_as_float(w << 16);
}
__device__ inline float bf2f_hi(unsigned int w) {
  return __uint_as_float(w & 0xffff0000u);
}

// ---------------- edge layout detect ----------------
__global__ void k_detect(const int* __restrict__ ei, int* __restrict__ flag) {
  int allz = 1;
  for (int i = 0; i < 32; ++i) allz &= (ei[2 * i + 1] == 0) ? 1 : 0;
  flag[0] = allz;
}

// ---------------- pack + degree + per-block window histogram ----------------
// pk[i] = (col<<16)|row ; deg[v] += 1 ; cnt[blk][w] = #edges of window w in chunk
__global__ void k_pack_count(const int* __restrict__ ei, const int* __restrict__ flag,
                             unsigned int* __restrict__ pk, int* __restrict__ deg,
                             int* __restrict__ cnt, int E, int nChunk) {
  __shared__ int hist[256];
  for (int t = threadIdx.x; t < 256; t += BLK) hist[t] = 0;
  __syncthreads();
  const bool i64 = flag[0] != 0;
  int beg = blockIdx.x * nChunk, end = min(beg + nChunk, E);
  for (int i = beg + threadIdx.x; i < end; i += BLK) {
    int row, col;
    if (i64) { row = ei[2 * i]; col = ei[2 * (E + i)]; }
    else     { row = ei[i];     col = ei[E + i]; }
    unsigned int p = ((unsigned int)col << 16) | (unsigned int)row;
    pk[i] = p;
    atomicAdd(&deg[col], 1);
    atomicAdd(&hist[col >> 8], 1);
  }
  __syncthreads();
  for (int t = threadIdx.x; t < 256; t += BLK) cnt[blockIdx.x * 256 + t] = hist[t];
}

// ---------------- degree -> dis, hierarchical scan ----------------
__global__ void k_dis(const int* __restrict__ deg, float* __restrict__ dis, int n) {
  int i = blockIdx.x * BLK + threadIdx.x;
  if (i < n) dis[i] = 1.0f / sqrtf((float)(deg[i] + 1));
}

__global__ void k_scan1(const int* __restrict__ deg, int* __restrict__ offs,
                        int* __restrict__ bsum, int n) {
  __shared__ int wsums[5];
  int i = blockIdx.x * BLK + threadIdx.x;
  int v = (i < n) ? deg[i] : 0;
  int lane = threadIdx.x & 63, w = threadIdx.x >> 6;
  int x = v;
  #pragma unroll
  for (int s = 1; s < 64; s <<= 1) { int t = __shfl_up(x, s); if (lane >= s) x += t; }
  if (lane == 63) wsums[w] = x;
  __syncthreads();
  if (threadIdx.x == 0) {
    int a = 0;
    for (int k = 0; k < 4; ++k) { int t = wsums[k]; wsums[k] = a; a += t; }
    wsums[4] = a;
  }
  __syncthreads();
  int incl = x + wsums[w];
  if (i < n) offs[i] = incl - v;
  if (threadIdx.x == 0) bsum[blockIdx.x] = wsums[4];
}

__global__ void k_scan2(int* __restrict__ bsum, int nb) {
  __shared__ int wsums[5];
  int v = (threadIdx.x < nb) ? bsum[threadIdx.x] : 0;
  int lane = threadIdx.x & 63, w = threadIdx.x >> 6;
  int x = v;
  #pragma unroll
  for (int s = 1; s < 64; s <<= 1) { int t = __shfl_up(x, s); if (lane >= s) x += t; }
  if (lane == 63) wsums[w] = x;
  __syncthreads();
  if (threadIdx.x == 0) {
    int a = 0;
    for (int k = 0; k < 4; ++k) { int t = wsums[k]; wsums[k] = a; a += t; }
    wsums[4] = a;
  }
  __syncthreads();
  int incl = x + wsums[w];
  if (threadIdx.x < nb) bsum[threadIdx.x] = incl - v;
}

__global__ void k_scan3(int* __restrict__ offs, const int* __restrict__ bsum,
                        int n, int E) {
  int i = blockIdx.x * BLK + threadIdx.x;
  if (i < n) offs[i] += bsum[i >> 8];
  if (i == 0) offs[n] = E;
}

// ---------------- base[blk][w] = offs[w*256] + prefix of cnt over blocks ----------------
__global__ void k_bscan(const int* __restrict__ offs, const int* __restrict__ cnt,
                        int* __restrict__ base, int N, int nbBlocks) {
  int w = threadIdx.x;        // 0..255
  int start = offs[min(w * 256, N)];
  for (int b = 0; b < nbBlocks; ++b) {
    base[b * 256 + w] = start;
    start += cnt[b * 256 + w];
  }
}

// ---------------- partition edges into window-contiguous regions of P ----------------
__global__ void k_part_scatter(const unsigned int* __restrict__ pk,
                               const int* __restrict__ base,
                               unsigned int* __restrict__ P, int E, int nChunk) {
  __shared__ int cur[256];
  for (int t = threadIdx.x; t < 256; t += BLK) cur[t] = base[blockIdx.x * 256 + t];
  __syncthreads();
  int beg = blockIdx.x * nChunk, end = min(beg + nChunk, E);
  for (int i = beg + threadIdx.x; i < end; i += BLK) {
    unsigned int p = pk[i];
    int pos = atomicAdd(&cur[p >> 24], 1);
    P[pos] = p;
  }
}

// ---------------- within-window CSR scatter: one block per 256-node window ----------------
__global__ void k_csr_scatter(const unsigned int* __restrict__ P,
                              const int* __restrict__ offs,
                              int* __restrict__ csr, int N) {
  __shared__ int cur[256];
  int node0 = blockIdx.x * 256;
  int nmax = min(256, N - node0);
  for (int t = threadIdx.x; t < nmax; t += BLK) cur[t] = offs[node0 + t];
  __syncthreads();
  int beg = offs[node0], end = offs[min(node0 + 256, N)];
  for (int i = beg + threadIdx.x; i < end; i += BLK) {
    unsigned int p = P[i];
    int pos = atomicAdd(&cur[(p >> 16) & 255], 1);
    csr[pos] = (int)(p & 0xffffu);
  }
}

// ---------------- W (K x NOUT fp32) -> WT (NOUTP x K bf16, zero-padded) ----------------
template<int K, int NOUT, int NOUTP>
__global__ void k_wt(const float* __restrict__ W, unsigned short* __restrict__ WT) {
  int i = blockIdx.x * BLK + threadIdx.x;
  if (i >= NOUTP * K) return;
  int n = i / K, k = i % K;
  float v = (n < NOUT) ? W[(size_t)k * NOUT + n] : 0.f;
  WT[i] = f2bf(v);
}

// ---------------- MFMA GEMM: C[i][j] = (sum_k A[i][k]*W[k][j]) * (dis?dis[i]:1) ----------------
template<int K, int NT, int MR, bool AF32>
__launch_bounds__(256)
__global__ void k_mgemm(const void* __restrict__ Av, const unsigned short* __restrict__ WT,
                        const float* __restrict__ dis, unsigned short* __restrict__ C,
                        int ldc, int NOUT, int N) {
  const int tid = threadIdx.x;
  const int lane = tid & 63;
  const int wv = tid >> 6;
  const int m = lane & 15;          // operand outer index
  const int kq = lane >> 4;         // 0..3 (k-quad)
  const int orow = blockIdx.x * (64 * MR) + wv * (16 * MR);

  int rowc[MR];
  #pragma unroll
  for (int mr = 0; mr < MR; ++mr) {
    int row = orow + mr * 16 + m;
    rowc[mr] = row < N ? row : N - 1;   // clamp loads; store is guarded
  }

  f32x4 acc[MR][NT];
  #pragma unroll
  for (int mr = 0; mr < MR; ++mr)
    #pragma unroll
    for (int t = 0; t < NT; ++t) acc[mr][t] = {0.f, 0.f, 0.f, 0.f};

  #pragma unroll 2
  for (int k0 = 0; k0 < K; k0 += 32) {
    bf16x8 af[MR];
    #pragma unroll
    for (int mr = 0; mr < MR; ++mr) {
      if constexpr (AF32) {
        const float* Arow = (const float*)Av + (size_t)rowc[mr] * K + kq * 8 + k0;
        float4 a0 = *(const float4*)Arow;
        float4 a1 = *(const float4*)(Arow + 4);
        af[mr][0] = (short)f2bf(a0.x); af[mr][1] = (short)f2bf(a0.y);
        af[mr][2] = (short)f2bf(a0.z); af[mr][3] = (short)f2bf(a0.w);
        af[mr][4] = (short)f2bf(a1.x); af[mr][5] = (short)f2bf(a1.y);
        af[mr][6] = (short)f2bf(a1.z); af[mr][7] = (short)f2bf(a1.w);
      } else {
        const unsigned short* Arow = (const unsigned short*)Av + (size_t)rowc[mr] * K + kq * 8 + k0;
        af[mr] = *(const bf16x8*)Arow;
      }
    }
    bf16x8 bf[NT];
    #pragma unroll
    for (int t = 0; t < NT; ++t)
      bf[t] = *(const bf16x8*)(WT + (size_t)(t * 16 + m) * K + k0 + kq * 8);
    #pragma unroll
    for (int t = 0; t < NT; ++t)
      #pragma unroll
      for (int mr = 0; mr < MR; ++mr)
        acc[mr][t] = __builtin_amdgcn_mfma_f32_16x16x32_bf16(af[mr], bf[t], acc[mr][t], 0, 0, 0);
  }
  // C/D layout: col = lane&15 (=m), row = kq*4 + r
  #pragma unroll
  for (int mr = 0; mr < MR; ++mr) {
    #pragma unroll
    for (int r = 0; r < 4; ++r) {
      int rr = orow + mr * 16 + kq * 4 + r;
      if (rr < N) {
        float s = dis ? dis[rr] : 1.f;
        #pragma unroll
        for (int t = 0; t < NT; ++t) {
          int cc = t * 16 + m;
          if (cc < NOUT)
            C[(size_t)rr * ldc + cc] = f2bf(acc[mr][t][r] * s);
        }
      }
    }
  }
}

// ---------------- aggregation: out[v] = dis[v]*(g[v] + sum_in g[u]) + b ----------------
template<int D, bool RELU, bool LOGSM, bool OUTF32>
__launch_bounds__(BLK)
__global__ void k_agg(const unsigned short* __restrict__ g, int ldg,
                      const float* __restrict__ dis, const float* __restrict__ bias,
                      const int* __restrict__ offs, const int* __restrict__ csr,
                      void* __restrict__ dstv, int ldd, int N) {
  int wid = (blockIdx.x * BLK + threadIdx.x) >> 6;
  int lane = threadIdx.x & 63;
  if (wid >= N) return;
  float acc0 = 0.f, acc1 = 0.f;
  if constexpr (D == 128) {
    unsigned int w = *(const unsigned int*)&g[(size_t)wid * ldg + lane * 2];
    acc0 = bf2f_lo(w); acc1 = bf2f_hi(w);
  } else {
    if (lane < D) acc0 = bf2f(g[(size_t)wid * ldg + lane]);
  }
  int beg = offs[wid], end = offs[wid + 1];
  for (int e0 = beg; e0 < end; e0 += 64) {
    int cnt = end - e0; if (cnt > 64) cnt = 64;
    int u = (lane < cnt) ? csr[e0 + lane] : 0;
    int j = 0;
    for (; j + 3 < cnt; j += 4) {
      int u0 = __shfl(u, j), u1 = __shfl(u, j + 1);
      int u2 = __shfl(u, j + 2), u3 = __shfl(u, j + 3);
      if constexpr (D == 128) {
        unsigned int w0 = *(const unsigned int*)&g[(size_t)u0 * ldg + lane * 2];
        unsigned int w1 = *(const unsigned int*)&g[(size_t)u1 * ldg + lane * 2];
        unsigned int w2 = *(const unsigned int*)&g[(size_t)u2 * ldg + lane * 2];
        unsigned int w3 = *(const unsigned int*)&g[(size_t)u3 * ldg + lane * 2];
        acc0 += bf2f_lo(w0) + bf2f_lo(w1) + bf2f_lo(w2) + bf2f_lo(w3);
        acc1 += bf2f_hi(w0) + bf2f_hi(w1) + bf2f_hi(w2) + bf2f_hi(w3);
      } else {
        if (lane < D) {
          float v0 = bf2f(g[(size_t)u0 * ldg + lane]);
          float v1 = bf2f(g[(size_t)u1 * ldg + lane]);
          float v2 = bf2f(g[(size_t)u2 * ldg + lane]);
          float v3 = bf2f(g[(size_t)u3 * ldg + lane]);
          acc0 += (v0 + v1) + (v2 + v3);
        }
      }
    }
    for (; j < cnt; ++j) {
      int u0 = __shfl(u, j);
      if constexpr (D == 128) {
        unsigned int w0 = *(const unsigned int*)&g[(size_t)u0 * ldg + lane * 2];
        acc0 += bf2f_lo(w0); acc1 += bf2f_hi(w0);
      } else {
        if (lane < D) acc0 += bf2f(g[(size_t)u0 * ldg + lane]);
      }
    }
  }
  float dv = dis[wid];
  if constexpr (D == 128) {
    float ox = dv * acc0 + bias[lane * 2];
    float oy = dv * acc1 + bias[lane * 2 + 1];
    if constexpr (RELU) { ox = fmaxf(ox, 0.f); oy = fmaxf(oy, 0.f); }
    unsigned int pw = (unsigned int)f2bf(ox) | ((unsigned int)f2bf(oy) << 16);
    *(unsigned int*)&((unsigned short*)dstv)[(size_t)wid * ldd + lane * 2] = pw;
  } else {
    float o = 0.f;
    if (lane < D) o = dv * acc0 + bias[lane];
    if constexpr (RELU) o = fmaxf(o, 0.f);
    if constexpr (LOGSM) {
      float v = (lane < D) ? o : -__builtin_inff();
      float mx = v;
      #pragma unroll
      for (int s = 32; s >= 1; s >>= 1) mx = fmaxf(mx, __shfl_xor(mx, s));
      float ex = (lane < D) ? expf(v - mx) : 0.f;
      float sum = ex;
      #pragma unroll
      for (int s = 32; s >= 1; s >>= 1) sum += __shfl_xor(sum, s);
      o = v - mx - logf(sum);
    }
    if (lane < D) {
      if constexpr (OUTF32) ((float*)dstv)[(size_t)wid * ldd + lane] = o;
      else ((unsigned short*)dstv)[(size_t)wid * ldd + lane] = f2bf(o);
    }
  }
}

// ---------------- launcher ----------------
extern "C" void kernel_launch(void* const* d_in, const int* in_sizes, int n_in,
                              void* d_out, int out_size, void* d_ws, size_t ws_size,
                              hipStream_t stream) {
  const float* x    = (const float*)d_in[0];
  const int*   ei   = (const int*)d_in[1];
  const float* eig  = (const float*)d_in[2];
  const float* W1   = (const float*)d_in[3];
  const float* b1   = (const float*)d_in[4];
  const float* W2   = (const float*)d_in[5];
  const float* b2   = (const float*)d_in[6];
  const float* linW = (const float*)d_in[7];
  const float* W3   = (const float*)d_in[8];
  const float* b3   = (const float*)d_in[9];
  float* out = (float*)d_out;

  const int N = in_sizes[0] / 512;
  const int E = in_sizes[1] / 2;

  char* ws = (char*)d_ws;
  size_t off = 0;
  auto alloc = [&](size_t bytes) { char* p = ws + off; off = ws_align(off + bytes); return p; };
  unsigned int* pk = (unsigned int*)alloc((size_t)E * 4);   // packed (col<<16)|row
  unsigned int* P  = (unsigned int*)alloc((size_t)E * 4);   // window-partitioned edges
  int*   csr    = (int*)alloc((size_t)E * 4);
  int*   deg    = (int*)alloc((size_t)N * 4);
  int*   offs   = (int*)alloc((size_t)(N + 1) * 4);
  int*   cnt    = (int*)alloc((size_t)NB * 256 * 4);
  int*   base   = (int*)alloc((size_t)NB * 256 * 4);
  int*   bsum   = (int*)alloc(4096);
  int*   flag   = (int*)alloc(256);
  float* dis    = (float*)alloc((size_t)N * 4);
  unsigned short* F = (unsigned short*)alloc((size_t)N * 128 * 2);  // conv GEMM outputs, bf16
  unsigned short* G = (unsigned short*)alloc((size_t)N * 128 * 2);  // h1 then hcat, bf16
  unsigned short* WT1 = (unsigned short*)alloc(128 * 512 * 2);
  unsigned short* WT2 = (unsigned short*)alloc(64 * 128 * 2);
  unsigned short* WTl = (unsigned short*)alloc(64 * 128 * 2);
  unsigned short* WT3 = (unsigned short*)alloc(48 * 128 * 2);

  hipMemsetAsync(deg, 0, (size_t)N * 4, stream);

  const int gN = (N + BLK - 1) / BLK;
  const int nChunk = (E + NB - 1) / NB;
  const int NW = (N + 255) / 256;           // 256-node windows

  k_detect<<<1, 1, 0, stream>>>(ei, flag);
  k_pack_count<<<NB, BLK, 0, stream>>>(ei, flag, pk, deg, cnt, E, nChunk);
  k_dis<<<gN, BLK, 0, stream>>>(deg, dis, N);
  k_scan1<<<gN, BLK, 0, stream>>>(deg, offs, bsum, N);
  k_scan2<<<1, BLK, 0, stream>>>(bsum, gN);
  k_scan3<<<gN, BLK, 0, stream>>>(offs, bsum, N, E);
  k_bscan<<<1, 256, 0, stream>>>(offs, cnt, base, N, NB);
  k_part_scatter<<<NB, BLK, 0, stream>>>(pk, base, P, E, nChunk);
  k_csr_scatter<<<NW, BLK, 0, stream>>>(P, offs, csr, N);

  // weight conversions (tiny)
  k_wt<512, 128, 128><<<(128 * 512 + BLK - 1) / BLK, BLK, 0, stream>>>(W1, WT1);
  k_wt<128, 64, 64><<<(64 * 128 + BLK - 1) / BLK, BLK, 0, stream>>>(W2, WT2);
  k_wt<128, 64, 64><<<(64 * 128 + BLK - 1) / BLK, BLK, 0, stream>>>(linW, WTl);
  k_wt<128, 40, 48><<<(48 * 128 + BLK - 1) / BLK, BLK, 0, stream>>>(W3, WT3);

  const int gG2 = (N + 127) / 128;    // MFMA GEMM blocks (MR=2 -> 128 rows/block)
  const int gA = (N + 3) / 4;         // agg blocks (4 waves/block)

  // conv1: g1 = (x @ W1)*dis ; h1 = relu(dis*(g1[v]+sum) + b1)   [h1 -> G, bf16]
  k_mgemm<512, 8, 2, true><<<gG2, BLK, 0, stream>>>(x, WT1, dis, F, 128, 128, N);
  k_agg<128, true, false, false><<<gA, BLK, 0, stream>>>(F, 128, dis, b1, offs, csr, G, 128, N);
  // conv2: g2 = (h1 @ W2)*dis ; spectral xp = eig @ linW into right half of G
  k_mgemm<128, 4, 2, false><<<gG2, BLK, 0, stream>>>(G, WT2, dis, F, 64, 64, N);
  k_mgemm<128, 4, 2, true><<<gG2, BLK, 0, stream>>>(eig, WTl, nullptr, G + 64, 128, 64, N);
  k_agg<64, true, false, false><<<gA, BLK, 0, stream>>>(F, 64, dis, b2, offs, csr, G, 128, N);
  // conv3: g3 = (hcat @ W3)*dis ; out = log_softmax(dis*(g3[v]+sum)+b3)  [fp32 out]
  k_mgemm<128, 3, 2, false><<<gG2, BLK, 0, stream>>>(G, WT3, dis, F, 40, 40, N);
  k_agg<40, false, true, true><<<gA, BLK, 0, stream>>>(F, 40, dis, b3, offs, csr, out, 40, N);
}

// Round 7
// 334.427 us; speedup vs baseline: 1.2289x; 1.1805x over previous
//
#include <hip/hip_runtime.h>
#include <cstdint>
#include <cstddef>

constexpr int BLK = 256;
constexpr int NB = 128;          // partition blocks

static inline size_t ws_align(size_t x) { return (x + 255) & ~size_t(255); }

typedef __attribute__((ext_vector_type(8))) short bf16x8;
typedef __attribute__((ext_vector_type(4))) float f32x4;

__device__ inline unsigned short f2bf(float f) {
  unsigned int u = __float_as_uint(f);
  unsigned int r = (u + 0x7fffu + ((u >> 16) & 1u)) >> 16;   // RNE
  return (unsigned short)r;
}
__device__ inline float bf2f(unsigned short u) {
  return __uint_as_float(((unsigned int)u) << 16);
}
__device__ inline float bf2f_lo(unsigned int w) {
  return __uint_as_float(w << 16);
}
__device__ inline float bf2f_hi(unsigned int w) {
  return __uint_as_float(w & 0xffff0000u);
}

// ---------------- edge layout detect ----------------
__global__ void k_detect(const int* __restrict__ ei, int* __restrict__ flag) {
  int allz = 1;
  for (int i = 0; i < 32; ++i) allz &= (ei[2 * i + 1] == 0) ? 1 : 0;
  flag[0] = allz;
}

// ---------------- pack + per-block window histogram (LDS only, no global atomics) ----------------
// pk[i] = (col<<16)|row ; cnt[blk][w] = #edges of window w (col>>8) in this chunk
__global__ void k_pack_count(const int* __restrict__ ei, const int* __restrict__ flag,
                             unsigned int* __restrict__ pk,
                             int* __restrict__ cnt, int E, int nChunk) {
  __shared__ int hist[256];
  for (int t = threadIdx.x; t < 256; t += BLK) hist[t] = 0;
  __syncthreads();
  const bool i64 = flag[0] != 0;
  int beg = blockIdx.x * nChunk, end = min(beg + nChunk, E);
  for (int i = beg + threadIdx.x; i < end; i += BLK) {
    int row, col;
    if (i64) { row = ei[2 * i]; col = ei[2 * (E + i)]; }
    else     { row = ei[i];     col = ei[E + i]; }
    unsigned int p = ((unsigned int)col << 16) | (unsigned int)row;
    pk[i] = p;
    atomicAdd(&hist[col >> 8], 1);
  }
  __syncthreads();
  for (int t = threadIdx.x; t < 256; t += BLK) cnt[blockIdx.x * 256 + t] = hist[t];
}

// ---------------- window scan: woffs + per-(block,window) bases ----------------
// 1 block, 256 threads. woffs[w] = global start of window w; base[b][w] cursors.
__global__ void k_wscan(const int* __restrict__ cnt, int* __restrict__ woffs,
                        int* __restrict__ base, int nb, int E) {
  __shared__ int wsums[5];
  int w = threadIdx.x;
  int s = 0;
  for (int b = 0; b < nb; ++b) s += cnt[b * 256 + w];
  int lane = w & 63, wv = w >> 6;
  int x = s;
  #pragma unroll
  for (int sh = 1; sh < 64; sh <<= 1) { int t = __shfl_up(x, sh); if (lane >= sh) x += t; }
  if (lane == 63) wsums[wv] = x;
  __syncthreads();
  if (w == 0) { int a = 0; for (int k = 0; k < 4; ++k) { int t = wsums[k]; wsums[k] = a; a += t; } }
  __syncthreads();
  int excl = x - s + wsums[wv];
  woffs[w] = excl;
  if (w == 255) woffs[256] = excl + s;   // == E
  int start = excl;
  for (int b = 0; b < nb; ++b) { base[b * 256 + w] = start; start += cnt[b * 256 + w]; }
}

// ---------------- partition edges into window-contiguous regions of P ----------------
__global__ void k_part_scatter(const unsigned int* __restrict__ pk,
                               const int* __restrict__ base,
                               unsigned int* __restrict__ P, int E, int nChunk) {
  __shared__ int cur[256];
  for (int t = threadIdx.x; t < 256; t += BLK) cur[t] = base[blockIdx.x * 256 + t];
  __syncthreads();
  int beg = blockIdx.x * nChunk, end = min(beg + nChunk, E);
  for (int i = beg + threadIdx.x; i < end; i += BLK) {
    unsigned int p = pk[i];
    int pos = atomicAdd(&cur[p >> 24], 1);
    P[pos] = p;
  }
}

// ---------------- per-window build: deg -> dis, offs, csr (one block per window) ----------------
__global__ void k_window_build(const unsigned int* __restrict__ P,
                               const int* __restrict__ woffs,
                               float* __restrict__ dis, int* __restrict__ offs,
                               int* __restrict__ csr, int N, int E) {
  __shared__ int hist[256];
  __shared__ int wsums[5];
  __shared__ int lbase[256];
  const int node0 = blockIdx.x * 256;
  const int t = threadIdx.x;
  hist[t] = 0;
  __syncthreads();
  const int beg = woffs[blockIdx.x], end = woffs[blockIdx.x + 1];
  for (int i = beg + t; i < end; i += BLK)
    atomicAdd(&hist[(P[i] >> 16) & 255], 1);
  __syncthreads();
  const int dg = hist[t];
  if (node0 + t < N) dis[node0 + t] = 1.0f / sqrtf((float)(dg + 1));
  // exclusive block scan of hist
  int lane = t & 63, wv = t >> 6;
  int x = dg;
  #pragma unroll
  for (int sh = 1; sh < 64; sh <<= 1) { int q = __shfl_up(x, sh); if (lane >= sh) x += q; }
  if (lane == 63) wsums[wv] = x;
  __syncthreads();
  if (t == 0) { int a = 0; for (int k = 0; k < 4; ++k) { int q = wsums[k]; wsums[k] = a; a += q; } }
  __syncthreads();
  const int goff = beg + (x - dg + wsums[wv]);
  if (node0 + t < N) offs[node0 + t] = goff;
  lbase[t] = goff;
  __syncthreads();
  for (int i = beg + t; i < end; i += BLK) {
    unsigned int p = P[i];
    int pos = atomicAdd(&lbase[(p >> 16) & 255], 1);
    csr[pos] = (int)(p & 0xffffu);
  }
  if (blockIdx.x == 0 && t == 0) offs[N] = E;
}

// ---------------- W (K x NOUT fp32) -> WT (NOUTP x K bf16, zero-padded) ----------------
template<int K, int NOUT, int NOUTP>
__global__ void k_wt(const float* __restrict__ W, unsigned short* __restrict__ WT) {
  int i = blockIdx.x * BLK + threadIdx.x;
  if (i >= NOUTP * K) return;
  int n = i / K, k = i % K;
  float v = (n < NOUT) ? W[(size_t)k * NOUT + n] : 0.f;
  WT[i] = f2bf(v);
}

// ---------------- MFMA GEMM: C[i][j] = (sum_k A[i][k]*W[k][j]) * (dis?dis[i]:1) ----------------
template<int K, int NT, int MR, bool AF32>
__launch_bounds__(256)
__global__ void k_mgemm(const void* __restrict__ Av, const unsigned short* __restrict__ WT,
                        const float* __restrict__ dis, unsigned short* __restrict__ C,
                        int ldc, int NOUT, int N) {
  const int tid = threadIdx.x;
  const int lane = tid & 63;
  const int wv = tid >> 6;
  const int m = lane & 15;          // operand outer index
  const int kq = lane >> 4;         // 0..3 (k-quad)
  const int orow = blockIdx.x * (64 * MR) + wv * (16 * MR);

  int rowc[MR];
  #pragma unroll
  for (int mr = 0; mr < MR; ++mr) {
    int row = orow + mr * 16 + m;
    rowc[mr] = row < N ? row : N - 1;   // clamp loads; store is guarded
  }

  f32x4 acc[MR][NT];
  #pragma unroll
  for (int mr = 0; mr < MR; ++mr)
    #pragma unroll
    for (int t = 0; t < NT; ++t) acc[mr][t] = {0.f, 0.f, 0.f, 0.f};

  #pragma unroll 2
  for (int k0 = 0; k0 < K; k0 += 32) {
    bf16x8 af[MR];
    #pragma unroll
    for (int mr = 0; mr < MR; ++mr) {
      if constexpr (AF32) {
        const float* Arow = (const float*)Av + (size_t)rowc[mr] * K + kq * 8 + k0;
        float4 a0 = *(const float4*)Arow;
        float4 a1 = *(const float4*)(Arow + 4);
        af[mr][0] = (short)f2bf(a0.x); af[mr][1] = (short)f2bf(a0.y);
        af[mr][2] = (short)f2bf(a0.z); af[mr][3] = (short)f2bf(a0.w);
        af[mr][4] = (short)f2bf(a1.x); af[mr][5] = (short)f2bf(a1.y);
        af[mr][6] = (short)f2bf(a1.z); af[mr][7] = (short)f2bf(a1.w);
      } else {
        const unsigned short* Arow = (const unsigned short*)Av + (size_t)rowc[mr] * K + kq * 8 + k0;
        af[mr] = *(const bf16x8*)Arow;
      }
    }
    bf16x8 bf[NT];
    #pragma unroll
    for (int t = 0; t < NT; ++t)
      bf[t] = *(const bf16x8*)(WT + (size_t)(t * 16 + m) * K + k0 + kq * 8);
    #pragma unroll
    for (int t = 0; t < NT; ++t)
      #pragma unroll
      for (int mr = 0; mr < MR; ++mr)
        acc[mr][t] = __builtin_amdgcn_mfma_f32_16x16x32_bf16(af[mr], bf[t], acc[mr][t], 0, 0, 0);
  }
  // C/D layout: col = lane&15 (=m), row = kq*4 + r
  #pragma unroll
  for (int mr = 0; mr < MR; ++mr) {
    #pragma unroll
    for (int r = 0; r < 4; ++r) {
      int rr = orow + mr * 16 + kq * 4 + r;
      if (rr < N) {
        float s = dis ? dis[rr] : 1.f;
        #pragma unroll
        for (int t = 0; t < NT; ++t) {
          int cc = t * 16 + m;
          if (cc < NOUT)
            C[(size_t)rr * ldc + cc] = f2bf(acc[mr][t][r] * s);
        }
      }
    }
  }
}

// ---------------- aggregation: out[v] = dis[v]*(g[v] + sum_in g[u]) + b ----------------
template<int D, bool RELU, bool LOGSM, bool OUTF32>
__launch_bounds__(BLK)
__global__ void k_agg(const unsigned short* __restrict__ g, int ldg,
                      const float* __restrict__ dis, const float* __restrict__ bias,
                      const int* __restrict__ offs, const int* __restrict__ csr,
                      void* __restrict__ dstv, int ldd, int N) {
  int wid = (blockIdx.x * BLK + threadIdx.x) >> 6;
  int lane = threadIdx.x & 63;
  if (wid >= N) return;
  float acc0 = 0.f, acc1 = 0.f;
  if constexpr (D == 128) {
    unsigned int w = *(const unsigned int*)&g[(size_t)wid * ldg + lane * 2];
    acc0 = bf2f_lo(w); acc1 = bf2f_hi(w);
  } else {
    if (lane < D) acc0 = bf2f(g[(size_t)wid * ldg + lane]);
  }
  int beg = offs[wid], end = offs[wid + 1];
  for (int e0 = beg; e0 < end; e0 += 64) {
    int cnt = end - e0; if (cnt > 64) cnt = 64;
    int u = (lane < cnt) ? csr[e0 + lane] : 0;
    int j = 0;
    for (; j + 3 < cnt; j += 4) {
      int u0 = __shfl(u, j), u1 = __shfl(u, j + 1);
      int u2 = __shfl(u, j + 2), u3 = __shfl(u, j + 3);
      if constexpr (D == 128) {
        unsigned int w0 = *(const unsigned int*)&g[(size_t)u0 * ldg + lane * 2];
        unsigned int w1 = *(const unsigned int*)&g[(size_t)u1 * ldg + lane * 2];
        unsigned int w2 = *(const unsigned int*)&g[(size_t)u2 * ldg + lane * 2];
        unsigned int w3 = *(const unsigned int*)&g[(size_t)u3 * ldg + lane * 2];
        acc0 += bf2f_lo(w0) + bf2f_lo(w1) + bf2f_lo(w2) + bf2f_lo(w3);
        acc1 += bf2f_hi(w0) + bf2f_hi(w1) + bf2f_hi(w2) + bf2f_hi(w3);
      } else {
        if (lane < D) {
          float v0 = bf2f(g[(size_t)u0 * ldg + lane]);
          float v1 = bf2f(g[(size_t)u1 * ldg + lane]);
          float v2 = bf2f(g[(size_t)u2 * ldg + lane]);
          float v3 = bf2f(g[(size_t)u3 * ldg + lane]);
          acc0 += (v0 + v1) + (v2 + v3);
        }
      }
    }
    for (; j < cnt; ++j) {
      int u0 = __shfl(u, j);
      if constexpr (D == 128) {
        unsigned int w0 = *(const unsigned int*)&g[(size_t)u0 * ldg + lane * 2];
        acc0 += bf2f_lo(w0); acc1 += bf2f_hi(w0);
      } else {
        if (lane < D) acc0 += bf2f(g[(size_t)u0 * ldg + lane]);
      }
    }
  }
  float dv = dis[wid];
  if constexpr (D == 128) {
    float ox = dv * acc0 + bias[lane * 2];
    float oy = dv * acc1 + bias[lane * 2 + 1];
    if constexpr (RELU) { ox = fmaxf(ox, 0.f); oy = fmaxf(oy, 0.f); }
    unsigned int pw = (unsigned int)f2bf(ox) | ((unsigned int)f2bf(oy) << 16);
    *(unsigned int*)&((unsigned short*)dstv)[(size_t)wid * ldd + lane * 2] = pw;
  } else {
    float o = 0.f;
    if (lane < D) o = dv * acc0 + bias[lane];
    if constexpr (RELU) o = fmaxf(o, 0.f);
    if constexpr (LOGSM) {
      float v = (lane < D) ? o : -__builtin_inff();
      float mx = v;
      #pragma unroll
      for (int s = 32; s >= 1; s >>= 1) mx = fmaxf(mx, __shfl_xor(mx, s));
      float ex = (lane < D) ? expf(v - mx) : 0.f;
      float sum = ex;
      #pragma unroll
      for (int s = 32; s >= 1; s >>= 1) sum += __shfl_xor(sum, s);
      o = v - mx - logf(sum);
    }
    if (lane < D) {
      if constexpr (OUTF32) ((float*)dstv)[(size_t)wid * ldd + lane] = o;
      else ((unsigned short*)dstv)[(size_t)wid * ldd + lane] = f2bf(o);
    }
  }
}

// ---------------- launcher ----------------
extern "C" void kernel_launch(void* const* d_in, const int* in_sizes, int n_in,
                              void* d_out, int out_size, void* d_ws, size_t ws_size,
                              hipStream_t stream) {
  const float* x    = (const float*)d_in[0];
  const int*   ei   = (const int*)d_in[1];
  const float* eig  = (const float*)d_in[2];
  const float* W1   = (const float*)d_in[3];
  const float* b1   = (const float*)d_in[4];
  const float* W2   = (const float*)d_in[5];
  const float* b2   = (const float*)d_in[6];
  const float* linW = (const float*)d_in[7];
  const float* W3   = (const float*)d_in[8];
  const float* b3   = (const float*)d_in[9];
  float* out = (float*)d_out;

  const int N = in_sizes[0] / 512;
  const int E = in_sizes[1] / 2;

  char* ws = (char*)d_ws;
  size_t off = 0;
  auto alloc = [&](size_t bytes) { char* p = ws + off; off = ws_align(off + bytes); return p; };
  unsigned int* pk = (unsigned int*)alloc((size_t)E * 4);   // packed (col<<16)|row
  unsigned int* P  = (unsigned int*)alloc((size_t)E * 4);   // window-partitioned edges
  int*   csr    = (int*)alloc((size_t)E * 4);
  int*   offs   = (int*)alloc((size_t)(N + 1) * 4);
  int*   cnt    = (int*)alloc((size_t)NB * 256 * 4);
  int*   base   = (int*)alloc((size_t)NB * 256 * 4);
  int*   woffs  = (int*)alloc(257 * 4);
  int*   flag   = (int*)alloc(256);
  float* dis    = (float*)alloc((size_t)N * 4);
  unsigned short* F = (unsigned short*)alloc((size_t)N * 128 * 2);  // conv GEMM outputs, bf16
  unsigned short* G = (unsigned short*)alloc((size_t)N * 128 * 2);  // h1 then hcat, bf16
  unsigned short* WT1 = (unsigned short*)alloc(128 * 512 * 2);
  unsigned short* WT2 = (unsigned short*)alloc(64 * 128 * 2);
  unsigned short* WTl = (unsigned short*)alloc(64 * 128 * 2);
  unsigned short* WT3 = (unsigned short*)alloc(48 * 128 * 2);

  const int nChunk = (E + NB - 1) / NB;
  const int NW = (N + 255) / 256;           // 256-node windows

  k_detect<<<1, 1, 0, stream>>>(ei, flag);
  k_pack_count<<<NB, BLK, 0, stream>>>(ei, flag, pk, cnt, E, nChunk);
  k_wscan<<<1, 256, 0, stream>>>(cnt, woffs, base, NB, E);
  k_part_scatter<<<NB, BLK, 0, stream>>>(pk, base, P, E, nChunk);
  k_window_build<<<NW, BLK, 0, stream>>>(P, woffs, dis, offs, csr, N, E);

  // weight conversions (tiny)
  k_wt<512, 128, 128><<<(128 * 512 + BLK - 1) / BLK, BLK, 0, stream>>>(W1, WT1);
  k_wt<128, 64, 64><<<(64 * 128 + BLK - 1) / BLK, BLK, 0, stream>>>(W2, WT2);
  k_wt<128, 64, 64><<<(64 * 128 + BLK - 1) / BLK, BLK, 0, stream>>>(linW, WTl);
  k_wt<128, 40, 48><<<(48 * 128 + BLK - 1) / BLK, BLK, 0, stream>>>(W3, WT3);

  const int gG2 = (N + 127) / 128;    // MFMA GEMM blocks (MR=2 -> 128 rows/block)
  const int gA = (N + 3) / 4;         // agg blocks (4 waves/block)

  // conv1: g1 = (x @ W1)*dis ; h1 = relu(dis*(g1[v]+sum) + b1)   [h1 -> G, bf16]
  k_mgemm<512, 8, 2, true><<<gG2, BLK, 0, stream>>>(x, WT1, dis, F, 128, 128, N);
  k_agg<128, true, false, false><<<gA, BLK, 0, stream>>>(F, 128, dis, b1, offs, csr, G, 128, N);
  // conv2: g2 = (h1 @ W2)*dis ; spectral xp = eig @ linW into right half of G
  k_mgemm<128, 4, 2, false><<<gG2, BLK, 0, stream>>>(G, WT2, dis, F, 64, 64, N);
  k_mgemm<128, 4, 2, true><<<gG2, BLK, 0, stream>>>(eig, WTl, nullptr, G + 64, 128, 64, N);
  k_agg<64, true, false, false><<<gA, BLK, 0, stream>>>(F, 64, dis, b2, offs, csr, G, 128, N);
  // conv3: g3 = (hcat @ W3)*dis ; out = log_softmax(dis*(g3[v]+sum)+b3)  [fp32 out]
  k_mgemm<128, 3, 2, false><<<gG2, BLK, 0, stream>>>(G, WT3, dis, F, 40, 40, N);
  k_agg<40, false, true, true><<<gA, BLK, 0, stream>>>(F, 40, dis, b3, offs, csr, out, 40, N);
}

// Round 8
// 321.755 us; speedup vs baseline: 1.2773x; 1.0394x over previous
//
#include <hip/hip_runtime.h>
#include <cstdint>
#include <cstddef>

constexpr int BLK = 256;
constexpr int NB = 128;          // partition blocks

static inline size_t ws_align(size_t x) { return (x + 255) & ~size_t(255); }

typedef __attribute__((ext_vector_type(8))) short bf16x8;
typedef __attribute__((ext_vector_type(4))) float f32x4;

__device__ inline unsigned short f2bf(float f) {
  unsigned int u = __float_as_uint(f);
  unsigned int r = (u + 0x7fffu + ((u >> 16) & 1u)) >> 16;   // RNE
  return (unsigned short)r;
}
__device__ inline float bf2f(unsigned short u) {
  return __uint_as_float(((unsigned int)u) << 16);
}
__device__ inline float bf2f_lo(unsigned int w) {
  return __uint_as_float(w << 16);
}
__device__ inline float bf2f_hi(unsigned int w) {
  return __uint_as_float(w & 0xffff0000u);
}

// ---------------- edge layout detect ----------------
__global__ void k_detect(const int* __restrict__ ei, int* __restrict__ flag) {
  int allz = 1;
  for (int i = 0; i < 32; ++i) allz &= (ei[2 * i + 1] == 0) ? 1 : 0;
  flag[0] = allz;
}

// ---------------- pack + per-block window histogram (LDS only, no global atomics) ----------------
__global__ void k_pack_count(const int* __restrict__ ei, const int* __restrict__ flag,
                             unsigned int* __restrict__ pk,
                             int* __restrict__ cnt, int E, int nChunk) {
  __shared__ int hist[256];
  for (int t = threadIdx.x; t < 256; t += BLK) hist[t] = 0;
  __syncthreads();
  const bool i64 = flag[0] != 0;
  int beg = blockIdx.x * nChunk, end = min(beg + nChunk, E);
  for (int i = beg + threadIdx.x; i < end; i += BLK) {
    int row, col;
    if (i64) { row = ei[2 * i]; col = ei[2 * (E + i)]; }
    else     { row = ei[i];     col = ei[E + i]; }
    unsigned int p = ((unsigned int)col << 16) | (unsigned int)row;
    pk[i] = p;
    atomicAdd(&hist[col >> 8], 1);
  }
  __syncthreads();
  for (int t = threadIdx.x; t < 256; t += BLK) cnt[blockIdx.x * 256 + t] = hist[t];
}

// ---------------- window scan: woffs + per-(block,window) bases ----------------
__global__ void k_wscan(const int* __restrict__ cnt, int* __restrict__ woffs,
                        int* __restrict__ base, int nb, int E) {
  __shared__ int wsums[5];
  int w = threadIdx.x;
  int s = 0;
  for (int b = 0; b < nb; ++b) s += cnt[b * 256 + w];
  int lane = w & 63, wv = w >> 6;
  int x = s;
  #pragma unroll
  for (int sh = 1; sh < 64; sh <<= 1) { int t = __shfl_up(x, sh); if (lane >= sh) x += t; }
  if (lane == 63) wsums[wv] = x;
  __syncthreads();
  if (w == 0) { int a = 0; for (int k = 0; k < 4; ++k) { int t = wsums[k]; wsums[k] = a; a += t; } }
  __syncthreads();
  int excl = x - s + wsums[wv];
  woffs[w] = excl;
  if (w == 255) woffs[256] = excl + s;   // == E
  int start = excl;
  for (int b = 0; b < nb; ++b) { base[b * 256 + w] = start; start += cnt[b * 256 + w]; }
}

// ---------------- partition edges into window-contiguous regions of P ----------------
__global__ void k_part_scatter(const unsigned int* __restrict__ pk,
                               const int* __restrict__ base,
                               unsigned int* __restrict__ P, int E, int nChunk) {
  __shared__ int cur[256];
  for (int t = threadIdx.x; t < 256; t += BLK) cur[t] = base[blockIdx.x * 256 + t];
  __syncthreads();
  int beg = blockIdx.x * nChunk, end = min(beg + nChunk, E);
  for (int i = beg + threadIdx.x; i < end; i += BLK) {
    unsigned int p = pk[i];
    int pos = atomicAdd(&cur[p >> 24], 1);
    P[pos] = p;
  }
}

// ---------------- per-window build: deg -> dis, offs, csr ----------------
__global__ void k_window_build(const unsigned int* __restrict__ P,
                               const int* __restrict__ woffs,
                               float* __restrict__ dis, int* __restrict__ offs,
                               int* __restrict__ csr, int N, int E) {
  __shared__ int hist[256];
  __shared__ int wsums[5];
  __shared__ int lbase[256];
  const int node0 = blockIdx.x * 256;
  const int t = threadIdx.x;
  hist[t] = 0;
  __syncthreads();
  const int beg = woffs[blockIdx.x], end = woffs[blockIdx.x + 1];
  for (int i = beg + t; i < end; i += BLK)
    atomicAdd(&hist[(P[i] >> 16) & 255], 1);
  __syncthreads();
  const int dg = hist[t];
  if (node0 + t < N) dis[node0 + t] = 1.0f / sqrtf((float)(dg + 1));
  int lane = t & 63, wv = t >> 6;
  int x = dg;
  #pragma unroll
  for (int sh = 1; sh < 64; sh <<= 1) { int q = __shfl_up(x, sh); if (lane >= sh) x += q; }
  if (lane == 63) wsums[wv] = x;
  __syncthreads();
  if (t == 0) { int a = 0; for (int k = 0; k < 4; ++k) { int q = wsums[k]; wsums[k] = a; a += q; } }
  __syncthreads();
  const int goff = beg + (x - dg + wsums[wv]);
  if (node0 + t < N) offs[node0 + t] = goff;
  lbase[t] = goff;
  __syncthreads();
  for (int i = beg + t; i < end; i += BLK) {
    unsigned int p = P[i];
    int pos = atomicAdd(&lbase[(p >> 16) & 255], 1);
    csr[pos] = (int)(p & 0xffffu);
  }
  if (blockIdx.x == 0 && t == 0) offs[N] = E;
}

// ---------------- W (K x NOUT fp32) -> WT (NOUTP x K bf16, zero-padded) ----------------
template<int K, int NOUT, int NOUTP>
__global__ void k_wt(const float* __restrict__ W, unsigned short* __restrict__ WT) {
  int i = blockIdx.x * BLK + threadIdx.x;
  if (i >= NOUTP * K) return;
  int n = i / K, k = i % K;
  float v = (n < NOUT) ? W[(size_t)k * NOUT + n] : 0.f;
  WT[i] = f2bf(v);
}

// ---------------- GEMM1: LDS-tiled double-buffered (K=512, NOUT=128, fp32 A) ----------------
// Block: 128 rows x 128 cols, 4 waves; each wave 32 rows (MR=2) x 128 cols (NT=8).
// A staged fp32->bf16 reg->LDS; W staged bf16->LDS. XOR-swizzled 16B granules.
__global__ __launch_bounds__(256)
void k_gemm1(const float* __restrict__ x, const unsigned short* __restrict__ WT,
             const float* __restrict__ dis, unsigned short* __restrict__ C, int N) {
  __shared__ unsigned short As[2][128 * 64];
  __shared__ unsigned short Ws[2][128 * 64];
  const int tid = threadIdx.x;
  const int lane = tid & 63, wv = tid >> 6;
  const int m = lane & 15, kq = lane >> 4;
  const int row0 = blockIdx.x * 128;

  // staging: thread -> (row srow, half shalf); 32 floats / 32 bf16 per iter
  const int srow = tid >> 1, shalf = tid & 1;
  int sgrow = row0 + srow; if (sgrow >= N) sgrow = N - 1;     // clamp; store guarded
  const float* xsrc = x + (size_t)sgrow * 512 + shalf * 32;
  const unsigned short* wsrc = WT + (size_t)srow * 512 + shalf * 32;
  int swoff[4];
  #pragma unroll
  for (int q = 0; q < 4; ++q)
    swoff[q] = srow * 128 + ((shalf * 64 + q * 16) ^ ((srow & 7) << 4));

  f32x4 acc[2][8];
  #pragma unroll
  for (int mr = 0; mr < 2; ++mr)
    #pragma unroll
    for (int t = 0; t < 8; ++t) acc[mr][t] = {0.f, 0.f, 0.f, 0.f};

  float4 ar[8];
  uint4  wr[4];

  // ---- prologue: load + write tile 0 into buf 0
  #pragma unroll
  for (int q = 0; q < 8; ++q) ar[q] = *(const float4*)(xsrc + q * 4);
  #pragma unroll
  for (int q = 0; q < 4; ++q) wr[q] = *(const uint4*)(wsrc + q * 8);
  {
    char* Aw = (char*)As[0];
    char* Ww = (char*)Ws[0];
    #pragma unroll
    for (int q = 0; q < 4; ++q) {
      float4 a = ar[q * 2], b = ar[q * 2 + 1];
      uint4 v;
      v.x = (unsigned)f2bf(a.x) | ((unsigned)f2bf(a.y) << 16);
      v.y = (unsigned)f2bf(a.z) | ((unsigned)f2bf(a.w) << 16);
      v.z = (unsigned)f2bf(b.x) | ((unsigned)f2bf(b.y) << 16);
      v.w = (unsigned)f2bf(b.z) | ((unsigned)f2bf(b.w) << 16);
      *(uint4*)(Aw + swoff[q]) = v;
      *(uint4*)(Ww + swoff[q]) = wr[q];
    }
  }
  __syncthreads();

  #pragma unroll 1
  for (int i = 0; i < 8; ++i) {
    const int p = i & 1;
    if (i < 7) {     // issue next-tile global loads early (hide HBM under MFMA)
      const float* xs = xsrc + (i + 1) * 64;
      const unsigned short* wss = wsrc + (i + 1) * 64;
      #pragma unroll
      for (int q = 0; q < 8; ++q) ar[q] = *(const float4*)(xs + q * 4);
      #pragma unroll
      for (int q = 0; q < 4; ++q) wr[q] = *(const uint4*)(wss + q * 8);
    }
    // compute on buf p
    const char* Ab = (const char*)As[p];
    const char* Wb = (const char*)Ws[p];
    #pragma unroll
    for (int ks = 0; ks < 2; ++ks) {
      bf16x8 af[2], bf[8];
      #pragma unroll
      for (int mr = 0; mr < 2; ++mr) {
        int row = wv * 32 + mr * 16 + m;
        int byte = row * 128 + (((ks * 64) + kq * 16) ^ ((row & 7) << 4));
        af[mr] = *(const bf16x8*)(Ab + byte);
      }
      #pragma unroll
      for (int t = 0; t < 8; ++t) {
        int wrow = t * 16 + m;
        int byte = wrow * 128 + (((ks * 64) + kq * 16) ^ ((wrow & 7) << 4));
        bf[t] = *(const bf16x8*)(Wb + byte);
      }
      #pragma unroll
      for (int t = 0; t < 8; ++t)
        #pragma unroll
        for (int mr = 0; mr < 2; ++mr)
          acc[mr][t] = __builtin_amdgcn_mfma_f32_16x16x32_bf16(af[mr], bf[t], acc[mr][t], 0, 0, 0);
    }
    if (i < 7) {     // convert + write next tile into the other buffer
      char* Aw = (char*)As[p ^ 1];
      char* Ww = (char*)Ws[p ^ 1];
      #pragma unroll
      for (int q = 0; q < 4; ++q) {
        float4 a = ar[q * 2], b = ar[q * 2 + 1];
        uint4 v;
        v.x = (unsigned)f2bf(a.x) | ((unsigned)f2bf(a.y) << 16);
        v.y = (unsigned)f2bf(a.z) | ((unsigned)f2bf(a.w) << 16);
        v.z = (unsigned)f2bf(b.x) | ((unsigned)f2bf(b.y) << 16);
        v.w = (unsigned)f2bf(b.z) | ((unsigned)f2bf(b.w) << 16);
        *(uint4*)(Aw + swoff[q]) = v;
        *(uint4*)(Ww + swoff[q]) = wr[q];
      }
      __syncthreads();
    }
  }

  // epilogue: C[rr][cc] = acc * dis[rr]
  #pragma unroll
  for (int mr = 0; mr < 2; ++mr)
    #pragma unroll
    for (int r = 0; r < 4; ++r) {
      int rr = row0 + wv * 32 + mr * 16 + kq * 4 + r;
      if (rr < N) {
        float s = dis[rr];
        #pragma unroll
        for (int t = 0; t < 8; ++t)
          C[(size_t)rr * 128 + t * 16 + m] = f2bf(acc[mr][t][r] * s);
      }
    }
}

// ---------------- MFMA GEMM (small K): C[i][j] = (sum_k A[i][k]*W[k][j]) * (dis?dis[i]:1) ----------------
template<int K, int NT, int MR, bool AF32>
__launch_bounds__(256)
__global__ void k_mgemm(const void* __restrict__ Av, const unsigned short* __restrict__ WT,
                        const float* __restrict__ dis, unsigned short* __restrict__ C,
                        int ldc, int NOUT, int N) {
  const int tid = threadIdx.x;
  const int lane = tid & 63;
  const int wv = tid >> 6;
  const int m = lane & 15;
  const int kq = lane >> 4;
  const int orow = blockIdx.x * (64 * MR) + wv * (16 * MR);

  int rowc[MR];
  #pragma unroll
  for (int mr = 0; mr < MR; ++mr) {
    int row = orow + mr * 16 + m;
    rowc[mr] = row < N ? row : N - 1;
  }

  f32x4 acc[MR][NT];
  #pragma unroll
  for (int mr = 0; mr < MR; ++mr)
    #pragma unroll
    for (int t = 0; t < NT; ++t) acc[mr][t] = {0.f, 0.f, 0.f, 0.f};

  #pragma unroll 4
  for (int k0 = 0; k0 < K; k0 += 32) {
    bf16x8 af[MR];
    #pragma unroll
    for (int mr = 0; mr < MR; ++mr) {
      if constexpr (AF32) {
        const float* Arow = (const float*)Av + (size_t)rowc[mr] * K + kq * 8 + k0;
        float4 a0 = *(const float4*)Arow;
        float4 a1 = *(const float4*)(Arow + 4);
        af[mr][0] = (short)f2bf(a0.x); af[mr][1] = (short)f2bf(a0.y);
        af[mr][2] = (short)f2bf(a0.z); af[mr][3] = (short)f2bf(a0.w);
        af[mr][4] = (short)f2bf(a1.x); af[mr][5] = (short)f2bf(a1.y);
        af[mr][6] = (short)f2bf(a1.z); af[mr][7] = (short)f2bf(a1.w);
      } else {
        const unsigned short* Arow = (const unsigned short*)Av + (size_t)rowc[mr] * K + kq * 8 + k0;
        af[mr] = *(const bf16x8*)Arow;
      }
    }
    bf16x8 bf[NT];
    #pragma unroll
    for (int t = 0; t < NT; ++t)
      bf[t] = *(const bf16x8*)(WT + (size_t)(t * 16 + m) * K + k0 + kq * 8);
    #pragma unroll
    for (int t = 0; t < NT; ++t)
      #pragma unroll
      for (int mr = 0; mr < MR; ++mr)
        acc[mr][t] = __builtin_amdgcn_mfma_f32_16x16x32_bf16(af[mr], bf[t], acc[mr][t], 0, 0, 0);
  }
  #pragma unroll
  for (int mr = 0; mr < MR; ++mr) {
    #pragma unroll
    for (int r = 0; r < 4; ++r) {
      int rr = orow + mr * 16 + kq * 4 + r;
      if (rr < N) {
        float s = dis ? dis[rr] : 1.f;
        #pragma unroll
        for (int t = 0; t < NT; ++t) {
          int cc = t * 16 + m;
          if (cc < NOUT)
            C[(size_t)rr * ldc + cc] = f2bf(acc[mr][t][r] * s);
        }
      }
    }
  }
}

// ---------------- aggregation: out[v] = dis[v]*(g[v] + sum_in g[u]) + b ----------------
template<int D, bool RELU, bool LOGSM, bool OUTF32>
__launch_bounds__(BLK)
__global__ void k_agg(const unsigned short* __restrict__ g, int ldg,
                      const float* __restrict__ dis, const float* __restrict__ bias,
                      const int* __restrict__ offs, const int* __restrict__ csr,
                      void* __restrict__ dstv, int ldd, int N) {
  int wid = (blockIdx.x * BLK + threadIdx.x) >> 6;
  int lane = threadIdx.x & 63;
  if (wid >= N) return;
  float acc0 = 0.f, acc1 = 0.f;
  if constexpr (D == 128) {
    unsigned int w = *(const unsigned int*)&g[(size_t)wid * ldg + lane * 2];
    acc0 = bf2f_lo(w); acc1 = bf2f_hi(w);
  } else {
    if (lane < D) acc0 = bf2f(g[(size_t)wid * ldg + lane]);
  }
  int beg = offs[wid], end = offs[wid + 1];
  for (int e0 = beg; e0 < end; e0 += 64) {
    int cnt = end - e0; if (cnt > 64) cnt = 64;
    int u = (lane < cnt) ? csr[e0 + lane] : 0;
    int j = 0;
    for (; j + 3 < cnt; j += 4) {
      int u0 = __shfl(u, j), u1 = __shfl(u, j + 1);
      int u2 = __shfl(u, j + 2), u3 = __shfl(u, j + 3);
      if constexpr (D == 128) {
        unsigned int w0 = *(const unsigned int*)&g[(size_t)u0 * ldg + lane * 2];
        unsigned int w1 = *(const unsigned int*)&g[(size_t)u1 * ldg + lane * 2];
        unsigned int w2 = *(const unsigned int*)&g[(size_t)u2 * ldg + lane * 2];
        unsigned int w3 = *(const unsigned int*)&g[(size_t)u3 * ldg + lane * 2];
        acc0 += bf2f_lo(w0) + bf2f_lo(w1) + bf2f_lo(w2) + bf2f_lo(w3);
        acc1 += bf2f_hi(w0) + bf2f_hi(w1) + bf2f_hi(w2) + bf2f_hi(w3);
      } else {
        if (lane < D) {
          float v0 = bf2f(g[(size_t)u0 * ldg + lane]);
          float v1 = bf2f(g[(size_t)u1 * ldg + lane]);
          float v2 = bf2f(g[(size_t)u2 * ldg + lane]);
          float v3 = bf2f(g[(size_t)u3 * ldg + lane]);
          acc0 += (v0 + v1) + (v2 + v3);
        }
      }
    }
    for (; j < cnt; ++j) {
      int u0 = __shfl(u, j);
      if constexpr (D == 128) {
        unsigned int w0 = *(const unsigned int*)&g[(size_t)u0 * ldg + lane * 2];
        acc0 += bf2f_lo(w0); acc1 += bf2f_hi(w0);
      } else {
        if (lane < D) acc0 += bf2f(g[(size_t)u0 * ldg + lane]);
      }
    }
  }
  float dv = dis[wid];
  if constexpr (D == 128) {
    float ox = dv * acc0 + bias[lane * 2];
    float oy = dv * acc1 + bias[lane * 2 + 1];
    if constexpr (RELU) { ox = fmaxf(ox, 0.f); oy = fmaxf(oy, 0.f); }
    unsigned int pw = (unsigned int)f2bf(ox) | ((unsigned int)f2bf(oy) << 16);
    *(unsigned int*)&((unsigned short*)dstv)[(size_t)wid * ldd + lane * 2] = pw;
  } else {
    float o = 0.f;
    if (lane < D) o = dv * acc0 + bias[lane];
    if constexpr (RELU) o = fmaxf(o, 0.f);
    if constexpr (LOGSM) {
      float v = (lane < D) ? o : -__builtin_inff();
      float mx = v;
      #pragma unroll
      for (int s = 32; s >= 1; s >>= 1) mx = fmaxf(mx, __shfl_xor(mx, s));
      float ex = (lane < D) ? expf(v - mx) : 0.f;
      float sum = ex;
      #pragma unroll
      for (int s = 32; s >= 1; s >>= 1) sum += __shfl_xor(sum, s);
      o = v - mx - logf(sum);
    }
    if (lane < D) {
      if constexpr (OUTF32) ((float*)dstv)[(size_t)wid * ldd + lane] = o;
      else ((unsigned short*)dstv)[(size_t)wid * ldd + lane] = f2bf(o);
    }
  }
}

// ---------------- launcher ----------------
extern "C" void kernel_launch(void* const* d_in, const int* in_sizes, int n_in,
                              void* d_out, int out_size, void* d_ws, size_t ws_size,
                              hipStream_t stream) {
  const float* x    = (const float*)d_in[0];
  const int*   ei   = (const int*)d_in[1];
  const float* eig  = (const float*)d_in[2];
  const float* W1   = (const float*)d_in[3];
  const float* b1   = (const float*)d_in[4];
  const float* W2   = (const float*)d_in[5];
  const float* b2   = (const float*)d_in[6];
  const float* linW = (const float*)d_in[7];
  const float* W3   = (const float*)d_in[8];
  const float* b3   = (const float*)d_in[9];
  float* out = (float*)d_out;

  const int N = in_sizes[0] / 512;
  const int E = in_sizes[1] / 2;

  char* ws = (char*)d_ws;
  size_t off = 0;
  auto alloc = [&](size_t bytes) { char* p = ws + off; off = ws_align(off + bytes); return p; };
  unsigned int* pk = (unsigned int*)alloc((size_t)E * 4);   // packed (col<<16)|row
  unsigned int* P  = (unsigned int*)alloc((size_t)E * 4);   // window-partitioned edges
  int*   csr    = (int*)alloc((size_t)E * 4);
  int*   offs   = (int*)alloc((size_t)(N + 1) * 4);
  int*   cnt    = (int*)alloc((size_t)NB * 256 * 4);
  int*   base   = (int*)alloc((size_t)NB * 256 * 4);
  int*   woffs  = (int*)alloc(257 * 4);
  int*   flag   = (int*)alloc(256);
  float* dis    = (float*)alloc((size_t)N * 4);
  unsigned short* F = (unsigned short*)alloc((size_t)N * 128 * 2);  // conv GEMM outputs, bf16
  unsigned short* G = (unsigned short*)alloc((size_t)N * 128 * 2);  // h1 then hcat, bf16
  unsigned short* WT1 = (unsigned short*)alloc(128 * 512 * 2);
  unsigned short* WT2 = (unsigned short*)alloc(64 * 128 * 2);
  unsigned short* WTl = (unsigned short*)alloc(64 * 128 * 2);
  unsigned short* WT3 = (unsigned short*)alloc(48 * 128 * 2);

  const int nChunk = (E + NB - 1) / NB;
  const int NW = (N + 255) / 256;           // 256-node windows

  k_detect<<<1, 1, 0, stream>>>(ei, flag);
  k_pack_count<<<NB, BLK, 0, stream>>>(ei, flag, pk, cnt, E, nChunk);
  k_wscan<<<1, 256, 0, stream>>>(cnt, woffs, base, NB, E);
  k_part_scatter<<<NB, BLK, 0, stream>>>(pk, base, P, E, nChunk);
  k_window_build<<<NW, BLK, 0, stream>>>(P, woffs, dis, offs, csr, N, E);

  // weight conversions (tiny)
  k_wt<512, 128, 128><<<(128 * 512 + BLK - 1) / BLK, BLK, 0, stream>>>(W1, WT1);
  k_wt<128, 64, 64><<<(64 * 128 + BLK - 1) / BLK, BLK, 0, stream>>>(W2, WT2);
  k_wt<128, 64, 64><<<(64 * 128 + BLK - 1) / BLK, BLK, 0, stream>>>(linW, WTl);
  k_wt<128, 40, 48><<<(48 * 128 + BLK - 1) / BLK, BLK, 0, stream>>>(W3, WT3);

  const int gG1 = (N + 127) / 128;    // k_gemm1 blocks (128 rows/block)
  const int gG2 = (N + 127) / 128;    // k_mgemm MR=2 blocks
  const int gA = (N + 3) / 4;         // agg blocks (4 waves/block)

  // conv1: g1 = (x @ W1)*dis ; h1 = relu(dis*(g1[v]+sum) + b1)   [h1 -> G, bf16]
  k_gemm1<<<gG1, BLK, 0, stream>>>(x, WT1, dis, F, N);
  k_agg<128, true, false, false><<<gA, BLK, 0, stream>>>(F, 128, dis, b1, offs, csr, G, 128, N);
  // conv2: g2 = (h1 @ W2)*dis ; spectral xp = eig @ linW into right half of G
  k_mgemm<128, 4, 2, false><<<gG2, BLK, 0, stream>>>(G, WT2, dis, F, 64, 64, N);
  k_mgemm<128, 4, 2, true><<<gG2, BLK, 0, stream>>>(eig, WTl, nullptr, G + 64, 128, 64, N);
  k_agg<64, true, false, false><<<gA, BLK, 0, stream>>>(F, 64, dis, b2, offs, csr, G, 128, N);
  // conv3: g3 = (hcat @ W3)*dis ; out = log_softmax(dis*(g3[v]+sum)+b3)  [fp32 out]
  k_mgemm<128, 3, 2, false><<<gG2, BLK, 0, stream>>>(G, WT3, dis, F, 40, 40, N);
  k_agg<40, false, true, true><<<gA, BLK, 0, stream>>>(F, 40, dis, b3, offs, csr, out, 40, N);
}

// Round 9
// 318.094 us; speedup vs baseline: 1.2920x; 1.0115x over previous
//
#include <hip/hip_runtime.h>
#include <cstdint>
#include <cstddef>

constexpr int BLK = 256;
constexpr int NB = 128;          // partition blocks

static inline size_t ws_align(size_t x) { return (x + 255) & ~size_t(255); }

typedef __attribute__((ext_vector_type(8))) short bf16x8;
typedef __attribute__((ext_vector_type(4))) float f32x4;

__device__ inline unsigned short f2bf(float f) {
  unsigned int u = __float_as_uint(f);
  unsigned int r = (u + 0x7fffu + ((u >> 16) & 1u)) >> 16;   // RNE
  return (unsigned short)r;
}
__device__ inline float bf2f(unsigned short u) {
  return __uint_as_float(((unsigned int)u) << 16);
}
__device__ inline float bf2f_lo(unsigned int w) {
  return __uint_as_float(w << 16);
}
__device__ inline float bf2f_hi(unsigned int w) {
  return __uint_as_float(w & 0xffff0000u);
}

// async global->LDS, 16B per lane; lds dest must be wave-uniform base (+lane*16 implicit)
__device__ inline void gload16(const void* gp, void* lp) {
  __builtin_amdgcn_global_load_lds(
      (const __attribute__((address_space(1))) void*)gp,
      (__attribute__((address_space(3))) void*)lp, 16, 0, 0);
}

// ---------------- edge layout detect ----------------
__global__ void k_detect(const int* __restrict__ ei, int* __restrict__ flag) {
  int allz = 1;
  for (int i = 0; i < 32; ++i) allz &= (ei[2 * i + 1] == 0) ? 1 : 0;
  flag[0] = allz;
}

// ---------------- pack + per-block window histogram (LDS only, no global atomics) ----------------
__global__ void k_pack_count(const int* __restrict__ ei, const int* __restrict__ flag,
                             unsigned int* __restrict__ pk,
                             int* __restrict__ cnt, int E, int nChunk) {
  __shared__ int hist[256];
  for (int t = threadIdx.x; t < 256; t += BLK) hist[t] = 0;
  __syncthreads();
  const bool i64 = flag[0] != 0;
  int beg = blockIdx.x * nChunk, end = min(beg + nChunk, E);
  for (int i = beg + threadIdx.x; i < end; i += BLK) {
    int row, col;
    if (i64) { row = ei[2 * i]; col = ei[2 * (E + i)]; }
    else     { row = ei[i];     col = ei[E + i]; }
    unsigned int p = ((unsigned int)col << 16) | (unsigned int)row;
    pk[i] = p;
    atomicAdd(&hist[col >> 8], 1);
  }
  __syncthreads();
  for (int t = threadIdx.x; t < 256; t += BLK) cnt[blockIdx.x * 256 + t] = hist[t];
}

// ---------------- window scan: woffs + per-(block,window) bases ----------------
__global__ void k_wscan(const int* __restrict__ cnt, int* __restrict__ woffs,
                        int* __restrict__ base, int nb, int E) {
  __shared__ int wsums[5];
  int w = threadIdx.x;
  int s = 0;
  for (int b = 0; b < nb; ++b) s += cnt[b * 256 + w];
  int lane = w & 63, wv = w >> 6;
  int x = s;
  #pragma unroll
  for (int sh = 1; sh < 64; sh <<= 1) { int t = __shfl_up(x, sh); if (lane >= sh) x += t; }
  if (lane == 63) wsums[wv] = x;
  __syncthreads();
  if (w == 0) { int a = 0; for (int k = 0; k < 4; ++k) { int t = wsums[k]; wsums[k] = a; a += t; } }
  __syncthreads();
  int excl = x - s + wsums[wv];
  woffs[w] = excl;
  if (w == 255) woffs[256] = excl + s;   // == E
  int start = excl;
  for (int b = 0; b < nb; ++b) { base[b * 256 + w] = start; start += cnt[b * 256 + w]; }
}

// ---------------- partition edges into window-contiguous regions of P ----------------
__global__ void k_part_scatter(const unsigned int* __restrict__ pk,
                               const int* __restrict__ base,
                               unsigned int* __restrict__ P, int E, int nChunk) {
  __shared__ int cur[256];
  for (int t = threadIdx.x; t < 256; t += BLK) cur[t] = base[blockIdx.x * 256 + t];
  __syncthreads();
  int beg = blockIdx.x * nChunk, end = min(beg + nChunk, E);
  for (int i = beg + threadIdx.x; i < end; i += BLK) {
    unsigned int p = pk[i];
    int pos = atomicAdd(&cur[p >> 24], 1);
    P[pos] = p;
  }
}

// ---------------- per-window build: deg -> dis, offs, csr ----------------
__global__ void k_window_build(const unsigned int* __restrict__ P,
                               const int* __restrict__ woffs,
                               float* __restrict__ dis, int* __restrict__ offs,
                               int* __restrict__ csr, int N, int E) {
  __shared__ int hist[256];
  __shared__ int wsums[5];
  __shared__ int lbase[256];
  const int node0 = blockIdx.x * 256;
  const int t = threadIdx.x;
  hist[t] = 0;
  __syncthreads();
  const int beg = woffs[blockIdx.x], end = woffs[blockIdx.x + 1];
  for (int i = beg + t; i < end; i += BLK)
    atomicAdd(&hist[(P[i] >> 16) & 255], 1);
  __syncthreads();
  const int dg = hist[t];
  if (node0 + t < N) dis[node0 + t] = 1.0f / sqrtf((float)(dg + 1));
  int lane = t & 63, wv = t >> 6;
  int x = dg;
  #pragma unroll
  for (int sh = 1; sh < 64; sh <<= 1) { int q = __shfl_up(x, sh); if (lane >= sh) x += q; }
  if (lane == 63) wsums[wv] = x;
  __syncthreads();
  if (t == 0) { int a = 0; for (int k = 0; k < 4; ++k) { int q = wsums[k]; wsums[k] = a; a += q; } }
  __syncthreads();
  const int goff = beg + (x - dg + wsums[wv]);
  if (node0 + t < N) offs[node0 + t] = goff;
  lbase[t] = goff;
  __syncthreads();
  for (int i = beg + t; i < end; i += BLK) {
    unsigned int p = P[i];
    int pos = atomicAdd(&lbase[(p >> 16) & 255], 1);
    csr[pos] = (int)(p & 0xffffu);
  }
  if (blockIdx.x == 0 && t == 0) offs[N] = E;
}

// ---------------- W (K x NOUT fp32) -> WT (NOUTP x K bf16, zero-padded) ----------------
template<int K, int NOUT, int NOUTP>
__global__ void k_wt(const float* __restrict__ W, unsigned short* __restrict__ WT) {
  int i = blockIdx.x * BLK + threadIdx.x;
  if (i >= NOUTP * K) return;
  int n = i / K, k = i % K;
  float v = (n < NOUT) ? W[(size_t)k * NOUT + n] : 0.f;
  WT[i] = f2bf(v);
}

// ---------------- GEMM1: global_load_lds double-buffered (K=512, NOUT=128, fp32 A) ----------------
__global__ __launch_bounds__(256)
void k_gemm1(const float* __restrict__ x, const unsigned short* __restrict__ WT,
             const float* __restrict__ dis, unsigned short* __restrict__ C, int N) {
  __shared__ float As[2][128 * 32];            // 2 x 16 KB
  __shared__ unsigned short Wsl[2][4 * 128 * 8]; // 2 x 8 KB, [slot][wrow][8]
  const int tid = threadIdx.x;
  const int lane = tid & 63, wv = tid >> 6;
  const int m = lane & 15, kq = lane >> 4;
  const int row0 = blockIdx.x * 128;

  const int r8 = lane >> 3;           // A: row within 8-row issue
  const int c8 = lane & 7;            // A: 16B slot within 128B row
  int agrow[4];
  #pragma unroll
  for (int jj = 0; jj < 4; ++jj) {
    int gr = row0 + wv * 32 + jj * 8 + r8;
    agrow[jj] = gr < N ? gr : N - 1;
  }

  f32x4 acc[2][8];
  #pragma unroll
  for (int mr = 0; mr < 2; ++mr)
    #pragma unroll
    for (int t = 0; t < 8; ++t) acc[mr][t] = {0.f, 0.f, 0.f, 0.f};

  auto STAGE = [&](int pb, int kb) {
    #pragma unroll
    for (int jj = 0; jj < 4; ++jj) {
      const float* src = x + (size_t)agrow[jj] * 512 + kb * 32 + (c8 ^ r8) * 4;
      gload16(src, &As[pb][(wv * 32 + jj * 8) * 32]);
    }
    #pragma unroll
    for (int jj = 0; jj < 2; ++jj) {
      int issue = wv * 2 + jj;
      int slot = issue >> 1, half = issue & 1;
      const unsigned short* src = WT + (size_t)(half * 64 + lane) * 512 + kb * 32 + slot * 8;
      gload16(src, &Wsl[pb][slot * 1024 + half * 512]);
    }
  };

  STAGE(0, 0);
  __syncthreads();

  #pragma unroll 1
  for (int t = 0; t < 16; ++t) {
    const int p = t & 1;
    if (t < 15) STAGE(p ^ 1, t + 1);

    const char* Ab = (const char*)As[p];
    const char* Wb = (const char*)Wsl[p];
    bf16x8 af[2];
    #pragma unroll
    for (int mr = 0; mr < 2; ++mr) {
      int row = wv * 32 + mr * 16 + m;
      int s = row & 7;
      f32x4 lo = *(const f32x4*)(Ab + row * 128 + ((kq * 2) ^ s) * 16);
      f32x4 hi = *(const f32x4*)(Ab + row * 128 + ((kq * 2 + 1) ^ s) * 16);
      af[mr][0] = (short)f2bf(lo[0]); af[mr][1] = (short)f2bf(lo[1]);
      af[mr][2] = (short)f2bf(lo[2]); af[mr][3] = (short)f2bf(lo[3]);
      af[mr][4] = (short)f2bf(hi[0]); af[mr][5] = (short)f2bf(hi[1]);
      af[mr][6] = (short)f2bf(hi[2]); af[mr][7] = (short)f2bf(hi[3]);
    }
    #pragma unroll
    for (int tt = 0; tt < 8; ++tt) {
      bf16x8 bf = *(const bf16x8*)(Wb + kq * 2048 + (tt * 16 + m) * 16);
      #pragma unroll
      for (int mr = 0; mr < 2; ++mr)
        acc[mr][tt] = __builtin_amdgcn_mfma_f32_16x16x32_bf16(af[mr], bf, acc[mr][tt], 0, 0, 0);
    }
    __syncthreads();
  }

  #pragma unroll
  for (int mr = 0; mr < 2; ++mr)
    #pragma unroll
    for (int r = 0; r < 4; ++r) {
      int rr = row0 + wv * 32 + mr * 16 + kq * 4 + r;
      if (rr < N) {
        float s = dis[rr];
        #pragma unroll
        for (int t = 0; t < 8; ++t)
          C[(size_t)rr * 128 + t * 16 + m] = f2bf(acc[mr][t][r] * s);
      }
    }
}

// ---------------- MFMA GEMM (small K) ----------------
template<int K, int NT, int MR, bool AF32>
__launch_bounds__(256)
__global__ void k_mgemm(const void* __restrict__ Av, const unsigned short* __restrict__ WT,
                        const float* __restrict__ dis, unsigned short* __restrict__ C,
                        int ldc, int NOUT, int N) {
  const int tid = threadIdx.x;
  const int lane = tid & 63;
  const int wv = tid >> 6;
  const int m = lane & 15;
  const int kq = lane >> 4;
  const int orow = blockIdx.x * (64 * MR) + wv * (16 * MR);

  int rowc[MR];
  #pragma unroll
  for (int mr = 0; mr < MR; ++mr) {
    int row = orow + mr * 16 + m;
    rowc[mr] = row < N ? row : N - 1;
  }

  f32x4 acc[MR][NT];
  #pragma unroll
  for (int mr = 0; mr < MR; ++mr)
    #pragma unroll
    for (int t = 0; t < NT; ++t) acc[mr][t] = {0.f, 0.f, 0.f, 0.f};

  #pragma unroll 4
  for (int k0 = 0; k0 < K; k0 += 32) {
    bf16x8 af[MR];
    #pragma unroll
    for (int mr = 0; mr < MR; ++mr) {
      if constexpr (AF32) {
        const float* Arow = (const float*)Av + (size_t)rowc[mr] * K + kq * 8 + k0;
        float4 a0 = *(const float4*)Arow;
        float4 a1 = *(const float4*)(Arow + 4);
        af[mr][0] = (short)f2bf(a0.x); af[mr][1] = (short)f2bf(a0.y);
        af[mr][2] = (short)f2bf(a0.z); af[mr][3] = (short)f2bf(a0.w);
        af[mr][4] = (short)f2bf(a1.x); af[mr][5] = (short)f2bf(a1.y);
        af[mr][6] = (short)f2bf(a1.z); af[mr][7] = (short)f2bf(a1.w);
      } else {
        const unsigned short* Arow = (const unsigned short*)Av + (size_t)rowc[mr] * K + kq * 8 + k0;
        af[mr] = *(const bf16x8*)Arow;
      }
    }
    bf16x8 bf[NT];
    #pragma unroll
    for (int t = 0; t < NT; ++t)
      bf[t] = *(const bf16x8*)(WT + (size_t)(t * 16 + m) * K + k0 + kq * 8);
    #pragma unroll
    for (int t = 0; t < NT; ++t)
      #pragma unroll
      for (int mr = 0; mr < MR; ++mr)
        acc[mr][t] = __builtin_amdgcn_mfma_f32_16x16x32_bf16(af[mr], bf[t], acc[mr][t], 0, 0, 0);
  }
  #pragma unroll
  for (int mr = 0; mr < MR; ++mr) {
    #pragma unroll
    for (int r = 0; r < 4; ++r) {
      int rr = orow + mr * 16 + kq * 4 + r;
      if (rr < N) {
        float s = dis ? dis[rr] : 1.f;
        #pragma unroll
        for (int t = 0; t < NT; ++t) {
          int cc = t * 16 + m;
          if (cc < NOUT)
            C[(size_t)rr * ldc + cc] = f2bf(acc[mr][t][r] * s);
        }
      }
    }
  }
}

// ---------------- aggregation v2: 32 lanes per row, 2 edges per load ----------------
// D in {64,128}. lanes<32 = edge j, lanes>=32 = edge j+1; fold via shfl_xor(32).
template<int D, bool RELU>
__launch_bounds__(BLK)
__global__ void k_agg2(const unsigned short* __restrict__ g, int ldg,
                       const float* __restrict__ dis, const float* __restrict__ bias,
                       const int* __restrict__ offs, const int* __restrict__ csr,
                       unsigned short* __restrict__ dst, int ldd, int N) {
  constexpr int CPL = D / 32;                 // cols per lane: 4 (D=128) or 2 (D=64)
  int wid = (blockIdx.x * BLK + threadIdx.x) >> 6;
  int lane = threadIdx.x & 63;
  if (wid >= N) return;
  const int l5 = lane >> 5, c = lane & 31;
  float acc[CPL];
  #pragma unroll
  for (int k = 0; k < CPL; ++k) acc[k] = 0.f;

  auto addrow = [&](int r) {
    if constexpr (CPL == 4) {
      uint2 w = *(const uint2*)&g[(size_t)r * ldg + c * 4];
      acc[0] += bf2f_lo(w.x); acc[1] += bf2f_hi(w.x);
      acc[2] += bf2f_lo(w.y); acc[3] += bf2f_hi(w.y);
    } else {
      unsigned int w = *(const unsigned int*)&g[(size_t)r * ldg + c * 2];
      acc[0] += bf2f_lo(w); acc[1] += bf2f_hi(w);
    }
  };

  if (l5 == 0) addrow(wid);                   // self row, counted once
  int beg = offs[wid], end = offs[wid + 1];
  for (int e0 = beg; e0 < end; e0 += 64) {
    int cnt = end - e0; if (cnt > 64) cnt = 64;
    int u = (lane < cnt) ? csr[e0 + lane] : 0;
    int j = 0;
    for (; j + 3 < cnt; j += 4) {
      int r0 = __shfl(u, j + l5);
      int r1 = __shfl(u, j + 2 + l5);
      addrow(r0); addrow(r1);
    }
    for (; j < cnt; j += 2) {
      int jj = j + l5;
      int r0 = __shfl(u, jj < cnt ? jj : j);
      if (jj < cnt) addrow(r0);
    }
  }
  #pragma unroll
  for (int k = 0; k < CPL; ++k) acc[k] += __shfl_xor(acc[k], 32);

  if (l5 == 0) {
    float dv = dis[wid];
    float o[CPL];
    #pragma unroll
    for (int k = 0; k < CPL; ++k) {
      o[k] = dv * acc[k] + bias[c * CPL + k];
      if constexpr (RELU) o[k] = fmaxf(o[k], 0.f);
    }
    if constexpr (CPL == 4) {
      uint2 pw;
      pw.x = (unsigned)f2bf(o[0]) | ((unsigned)f2bf(o[1]) << 16);
      pw.y = (unsigned)f2bf(o[2]) | ((unsigned)f2bf(o[3]) << 16);
      *(uint2*)&dst[(size_t)wid * ldd + c * 4] = pw;
    } else {
      unsigned int pw = (unsigned)f2bf(o[0]) | ((unsigned)f2bf(o[1]) << 16);
      *(unsigned int*)&dst[(size_t)wid * ldd + c * 2] = pw;
    }
  }
}

// ---------------- aggregation D=40 + log_softmax, fp32 out ----------------
// 20 active lanes per row (2 cols each); halves process edges j / j+1.
__launch_bounds__(BLK)
__global__ void k_agg40(const unsigned short* __restrict__ g,
                        const float* __restrict__ dis, const float* __restrict__ bias,
                        const int* __restrict__ offs, const int* __restrict__ csr,
                        float* __restrict__ dst, int N) {
  int wid = (blockIdx.x * BLK + threadIdx.x) >> 6;
  int lane = threadIdx.x & 63;
  if (wid >= N) return;
  const int l5 = lane >> 5, c = lane & 31;
  const bool act = c < 20;
  float a0 = 0.f, a1 = 0.f;
  auto addrow = [&](int r) {
    if (act) {
      unsigned int w = *(const unsigned int*)&g[(size_t)r * 40 + c * 2];
      a0 += bf2f_lo(w); a1 += bf2f_hi(w);
    }
  };
  if (l5 == 0) addrow(wid);
  int beg = offs[wid], end = offs[wid + 1];
  for (int e0 = beg; e0 < end; e0 += 64) {
    int cnt = end - e0; if (cnt > 64) cnt = 64;
    int u = (lane < cnt) ? csr[e0 + lane] : 0;
    int j = 0;
    for (; j + 3 < cnt; j += 4) {
      int r0 = __shfl(u, j + l5);
      int r1 = __shfl(u, j + 2 + l5);
      addrow(r0); addrow(r1);
    }
    for (; j < cnt; j += 2) {
      int jj = j + l5;
      int r0 = __shfl(u, jj < cnt ? jj : j);
      if (jj < cnt) addrow(r0);
    }
  }
  a0 += __shfl_xor(a0, 32);
  a1 += __shfl_xor(a1, 32);

  if (l5 == 0) {
    float dv = dis[wid];
    float o0 = act ? dv * a0 + bias[c * 2]     : -__builtin_inff();
    float o1 = act ? dv * a1 + bias[c * 2 + 1] : -__builtin_inff();
    float mx = fmaxf(o0, o1);
    #pragma unroll
    for (int s = 16; s >= 1; s >>= 1) mx = fmaxf(mx, __shfl_down(mx, s, 32));
    mx = __shfl(mx, 0, 32);
    float ex = act ? (expf(o0 - mx) + expf(o1 - mx)) : 0.f;
    #pragma unroll
    for (int s = 16; s >= 1; s >>= 1) ex += __shfl_down(ex, s, 32);
    float ls = logf(__shfl(ex, 0, 32));
    if (act) {
      float2 r = make_float2(o0 - mx - ls, o1 - mx - ls);
      *(float2*)&dst[(size_t)wid * 40 + c * 2] = r;
    }
  }
}

// ---------------- launcher ----------------
extern "C" void kernel_launch(void* const* d_in, const int* in_sizes, int n_in,
                              void* d_out, int out_size, void* d_ws, size_t ws_size,
                              hipStream_t stream) {
  const float* x    = (const float*)d_in[0];
  const int*   ei   = (const int*)d_in[1];
  const float* eig  = (const float*)d_in[2];
  const float* W1   = (const float*)d_in[3];
  const float* b1   = (const float*)d_in[4];
  const float* W2   = (const float*)d_in[5];
  const float* b2   = (const float*)d_in[6];
  const float* linW = (const float*)d_in[7];
  const float* W3   = (const float*)d_in[8];
  const float* b3   = (const float*)d_in[9];
  float* out = (float*)d_out;

  const int N = in_sizes[0] / 512;
  const int E = in_sizes[1] / 2;

  char* ws = (char*)d_ws;
  size_t off = 0;
  auto alloc = [&](size_t bytes) { char* p = ws + off; off = ws_align(off + bytes); return p; };
  unsigned int* pk = (unsigned int*)alloc((size_t)E * 4);   // packed (col<<16)|row
  unsigned int* P  = (unsigned int*)alloc((size_t)E * 4);   // window-partitioned edges
  int*   csr    = (int*)alloc((size_t)E * 4);
  int*   offs   = (int*)alloc((size_t)(N + 1) * 4);
  int*   cnt    = (int*)alloc((size_t)NB * 256 * 4);
  int*   base   = (int*)alloc((size_t)NB * 256 * 4);
  int*   woffs  = (int*)alloc(257 * 4);
  int*   flag   = (int*)alloc(256);
  float* dis    = (float*)alloc((size_t)N * 4);
  unsigned short* F = (unsigned short*)alloc((size_t)N * 128 * 2);  // conv GEMM outputs, bf16
  unsigned short* G = (unsigned short*)alloc((size_t)N * 128 * 2);  // h1 then hcat, bf16
  unsigned short* WT1 = (unsigned short*)alloc(128 * 512 * 2);
  unsigned short* WT2 = (unsigned short*)alloc(64 * 128 * 2);
  unsigned short* WTl = (unsigned short*)alloc(64 * 128 * 2);
  unsigned short* WT3 = (unsigned short*)alloc(48 * 128 * 2);

  const int nChunk = (E + NB - 1) / NB;
  const int NW = (N + 255) / 256;           // 256-node windows

  k_detect<<<1, 1, 0, stream>>>(ei, flag);
  k_pack_count<<<NB, BLK, 0, stream>>>(ei, flag, pk, cnt, E, nChunk);
  k_wscan<<<1, 256, 0, stream>>>(cnt, woffs, base, NB, E);
  k_part_scatter<<<NB, BLK, 0, stream>>>(pk, base, P, E, nChunk);
  k_window_build<<<NW, BLK, 0, stream>>>(P, woffs, dis, offs, csr, N, E);

  // weight conversions (tiny)
  k_wt<512, 128, 128><<<(128 * 512 + BLK - 1) / BLK, BLK, 0, stream>>>(W1, WT1);
  k_wt<128, 64, 64><<<(64 * 128 + BLK - 1) / BLK, BLK, 0, stream>>>(W2, WT2);
  k_wt<128, 64, 64><<<(64 * 128 + BLK - 1) / BLK, BLK, 0, stream>>>(linW, WTl);
  k_wt<128, 40, 48><<<(48 * 128 + BLK - 1) / BLK, BLK, 0, stream>>>(W3, WT3);

  const int gG1 = (N + 127) / 128;    // k_gemm1 blocks (128 rows/block)
  const int gG2 = (N + 127) / 128;    // k_mgemm MR=2 blocks
  const int gA = (N + 3) / 4;         // agg blocks (4 waves/block)

  // conv1: g1 = (x @ W1)*dis ; h1 = relu(dis*(g1[v]+sum) + b1)   [h1 -> G, bf16]
  k_gemm1<<<gG1, BLK, 0, stream>>>(x, WT1, dis, F, N);
  k_agg2<128, true><<<gA, BLK, 0, stream>>>(F, 128, dis, b1, offs, csr, G, 128, N);
  // conv2: g2 = (h1 @ W2)*dis ; spectral xp = eig @ linW into right half of G
  k_mgemm<128, 4, 2, false><<<gG2, BLK, 0, stream>>>(G, WT2, dis, F, 64, 64, N);
  k_mgemm<128, 4, 2, true><<<gG2, BLK, 0, stream>>>(eig, WTl, nullptr, G + 64, 128, 64, N);
  k_agg2<64, true><<<gA, BLK, 0, stream>>>(F, 64, dis, b2, offs, csr, G, 128, N);
  // conv3: g3 = (hcat @ W3)*dis ; out = log_softmax(dis*(g3[v]+sum)+b3)  [fp32 out]
  k_mgemm<128, 3, 2, false><<<gG2, BLK, 0, stream>>>(G, WT3, dis, F, 40, 40, N);
  k_agg40<<<gA, BLK, 0, stream>>>(F, dis, b3, offs, csr, out, N);
}

// Round 10
// 293.406 us; speedup vs baseline: 1.4007x; 1.0841x over previous
//
#include <hip/hip_runtime.h>
#include <cstdint>
#include <cstddef>

constexpr int BLK = 256;
constexpr int NB = 128;          // partition blocks

static inline size_t ws_align(size_t x) { return (x + 255) & ~size_t(255); }

typedef __attribute__((ext_vector_type(8))) short bf16x8;
typedef __attribute__((ext_vector_type(4))) float f32x4;

__device__ inline unsigned short f2bf(float f) {
  unsigned int u = __float_as_uint(f);
  unsigned int r = (u + 0x7fffu + ((u >> 16) & 1u)) >> 16;   // RNE
  return (unsigned short)r;
}
__device__ inline float bf2f(unsigned short u) {
  return __uint_as_float(((unsigned int)u) << 16);
}
__device__ inline float bf2f_lo(unsigned int w) {
  return __uint_as_float(w << 16);
}
__device__ inline float bf2f_hi(unsigned int w) {
  return __uint_as_float(w & 0xffff0000u);
}

// async global->LDS, 16B per lane; lds dest wave-uniform base (+lane*16 implicit)
__device__ inline void gload16(const void* gp, void* lp) {
  __builtin_amdgcn_global_load_lds(
      (const __attribute__((address_space(1))) void*)gp,
      (__attribute__((address_space(3))) void*)lp, 16, 0, 0);
}

// ---------------- pack (+inline layout detect) + per-block window histogram + wt tail ----------------
// blocks [0,NB): pack pk[i]=(col<<16)|row, cnt[blk][w]; blocks [NB,..): weight transposes.
__global__ void k_pack_wt(const int* __restrict__ ei, unsigned int* __restrict__ pk,
                          int* __restrict__ cnt, int E, int nChunk,
                          const float* __restrict__ W1, const float* __restrict__ W2,
                          const float* __restrict__ linW, const float* __restrict__ W3,
                          unsigned short* __restrict__ WT1, unsigned short* __restrict__ WT2,
                          unsigned short* __restrict__ WTl, unsigned short* __restrict__ WT3) {
  if (blockIdx.x >= NB) {
    int i = (blockIdx.x - NB) * BLK + threadIdx.x;   // flat wt index
    if (i < 65536) {                 // WT1: K=512, NOUT=128
      int n = i >> 9, k = i & 511;
      WT1[i] = f2bf(W1[(size_t)k * 128 + n]);
    } else if (i < 73728) {          // WT2: K=128, NOUT=64
      int j = i - 65536; int n = j >> 7, k = j & 127;
      WT2[j] = f2bf(W2[(size_t)k * 64 + n]);
    } else if (i < 81920) {          // WTl
      int j = i - 73728; int n = j >> 7, k = j & 127;
      WTl[j] = f2bf(linW[(size_t)k * 64 + n]);
    } else if (i < 88064) {          // WT3: K=128, NOUT=40, padded to 48
      int j = i - 81920; int n = j >> 7, k = j & 127;
      WT3[j] = f2bf(n < 40 ? W3[(size_t)k * 40 + n] : 0.f);
    }
    return;
  }
  __shared__ int hist[256];
  for (int t = threadIdx.x; t < 256; t += BLK) hist[t] = 0;
  __syncthreads();
  int allz = 1;
  #pragma unroll 8
  for (int i = 0; i < 32; ++i) allz &= (ei[2 * i + 1] == 0) ? 1 : 0;
  const bool i64 = allz != 0;
  int beg = blockIdx.x * nChunk, end = min(beg + nChunk, E);
  for (int i = beg + threadIdx.x; i < end; i += BLK) {
    int row, col;
    if (i64) { row = ei[2 * i]; col = ei[2 * (E + i)]; }
    else     { row = ei[i];     col = ei[E + i]; }
    unsigned int p = ((unsigned int)col << 16) | (unsigned int)row;
    pk[i] = p;
    atomicAdd(&hist[col >> 8], 1);
  }
  __syncthreads();
  for (int t = threadIdx.x; t < 256; t += BLK) cnt[blockIdx.x * 256 + t] = hist[t];
}

// ---------------- window scan: woffs + per-(block,window) bases ----------------
__global__ void k_wscan(const int* __restrict__ cnt, int* __restrict__ woffs,
                        int* __restrict__ base, int nb, int E) {
  __shared__ int wsums[5];
  int w = threadIdx.x;
  int s = 0;
  for (int b = 0; b < nb; ++b) s += cnt[b * 256 + w];
  int lane = w & 63, wv = w >> 6;
  int x = s;
  #pragma unroll
  for (int sh = 1; sh < 64; sh <<= 1) { int t = __shfl_up(x, sh); if (lane >= sh) x += t; }
  if (lane == 63) wsums[wv] = x;
  __syncthreads();
  if (w == 0) { int a = 0; for (int k = 0; k < 4; ++k) { int t = wsums[k]; wsums[k] = a; a += t; } }
  __syncthreads();
  int excl = x - s + wsums[wv];
  woffs[w] = excl;
  if (w == 255) woffs[256] = excl + s;   // == E
  int start = excl;
  for (int b = 0; b < nb; ++b) { base[b * 256 + w] = start; start += cnt[b * 256 + w]; }
}

// ---------------- partition edges into window-contiguous regions of P ----------------
__global__ void k_part_scatter(const unsigned int* __restrict__ pk,
                               const int* __restrict__ base,
                               unsigned int* __restrict__ P, int E, int nChunk) {
  __shared__ int cur[256];
  for (int t = threadIdx.x; t < 256; t += BLK) cur[t] = base[blockIdx.x * 256 + t];
  __syncthreads();
  int beg = blockIdx.x * nChunk, end = min(beg + nChunk, E);
  for (int i = beg + threadIdx.x; i < end; i += BLK) {
    unsigned int p = pk[i];
    int pos = atomicAdd(&cur[p >> 24], 1);
    P[pos] = p;
  }
}

// ---------------- per-window build: deg -> dis, offs, csr ----------------
__global__ void k_window_build(const unsigned int* __restrict__ P,
                               const int* __restrict__ woffs,
                               float* __restrict__ dis, int* __restrict__ offs,
                               int* __restrict__ csr, int N, int E) {
  __shared__ int hist[256];
  __shared__ int wsums[5];
  __shared__ int lbase[256];
  const int node0 = blockIdx.x * 256;
  const int t = threadIdx.x;
  hist[t] = 0;
  __syncthreads();
  const int beg = woffs[blockIdx.x], end = woffs[blockIdx.x + 1];
  for (int i = beg + t; i < end; i += BLK)
    atomicAdd(&hist[(P[i] >> 16) & 255], 1);
  __syncthreads();
  const int dg = hist[t];
  if (node0 + t < N) dis[node0 + t] = 1.0f / sqrtf((float)(dg + 1));
  int lane = t & 63, wv = t >> 6;
  int x = dg;
  #pragma unroll
  for (int sh = 1; sh < 64; sh <<= 1) { int q = __shfl_up(x, sh); if (lane >= sh) x += q; }
  if (lane == 63) wsums[wv] = x;
  __syncthreads();
  if (t == 0) { int a = 0; for (int k = 0; k < 4; ++k) { int q = wsums[k]; wsums[k] = a; a += q; } }
  __syncthreads();
  const int goff = beg + (x - dg + wsums[wv]);
  if (node0 + t < N) offs[node0 + t] = goff;
  lbase[t] = goff;
  __syncthreads();
  for (int i = beg + t; i < end; i += BLK) {
    unsigned int p = P[i];
    int pos = atomicAdd(&lbase[(p >> 16) & 255], 1);
    csr[pos] = (int)(p & 0xffffu);
  }
  if (blockIdx.x == 0 && t == 0) offs[N] = E;
}

// ---------------- GEMM1: global_load_lds double-buffered (K=512, NOUT=128, fp32 A) ----------------
__global__ __launch_bounds__(256)
void k_gemm1(const float* __restrict__ x, const unsigned short* __restrict__ WT,
             const float* __restrict__ dis, unsigned short* __restrict__ C, int N) {
  __shared__ float As[2][128 * 32];              // 2 x 16 KB
  __shared__ unsigned short Wsl[2][4 * 128 * 8]; // 2 x 8 KB, [slot][wrow][8]
  const int tid = threadIdx.x;
  const int lane = tid & 63, wv = tid >> 6;
  const int m = lane & 15, kq = lane >> 4;
  const int row0 = blockIdx.x * 128;

  const int r8 = lane >> 3;           // A: row within 8-row issue
  const int c8 = lane & 7;            // A: 16B slot within 128B row
  int agrow[4];
  #pragma unroll
  for (int jj = 0; jj < 4; ++jj) {
    int gr = row0 + wv * 32 + jj * 8 + r8;
    agrow[jj] = gr < N ? gr : N - 1;
  }

  f32x4 acc[2][8];
  #pragma unroll
  for (int mr = 0; mr < 2; ++mr)
    #pragma unroll
    for (int t = 0; t < 8; ++t) acc[mr][t] = {0.f, 0.f, 0.f, 0.f};

  auto STAGE = [&](int pb, int kb) {
    #pragma unroll
    for (int jj = 0; jj < 4; ++jj) {
      const float* src = x + (size_t)agrow[jj] * 512 + kb * 32 + (c8 ^ r8) * 4;
      gload16(src, &As[pb][(wv * 32 + jj * 8) * 32]);
    }
    #pragma unroll
    for (int jj = 0; jj < 2; ++jj) {
      int issue = wv * 2 + jj;
      int slot = issue >> 1, half = issue & 1;
      const unsigned short* src = WT + (size_t)(half * 64 + lane) * 512 + kb * 32 + slot * 8;
      gload16(src, &Wsl[pb][slot * 1024 + half * 512]);
    }
  };

  STAGE(0, 0);
  __syncthreads();

  #pragma unroll 1
  for (int t = 0; t < 16; ++t) {
    const int p = t & 1;
    if (t < 15) STAGE(p ^ 1, t + 1);

    const char* Ab = (const char*)As[p];
    const char* Wb = (const char*)Wsl[p];
    bf16x8 af[2];
    #pragma unroll
    for (int mr = 0; mr < 2; ++mr) {
      int row = wv * 32 + mr * 16 + m;
      int s = row & 7;
      f32x4 lo = *(const f32x4*)(Ab + row * 128 + ((kq * 2) ^ s) * 16);
      f32x4 hi = *(const f32x4*)(Ab + row * 128 + ((kq * 2 + 1) ^ s) * 16);
      af[mr][0] = (short)f2bf(lo[0]); af[mr][1] = (short)f2bf(lo[1]);
      af[mr][2] = (short)f2bf(lo[2]); af[mr][3] = (short)f2bf(lo[3]);
      af[mr][4] = (short)f2bf(hi[0]); af[mr][5] = (short)f2bf(hi[1]);
      af[mr][6] = (short)f2bf(hi[2]); af[mr][7] = (short)f2bf(hi[3]);
    }
    #pragma unroll
    for (int tt = 0; tt < 8; ++tt) {
      bf16x8 bf = *(const bf16x8*)(Wb + kq * 2048 + (tt * 16 + m) * 16);
      #pragma unroll
      for (int mr = 0; mr < 2; ++mr)
        acc[mr][tt] = __builtin_amdgcn_mfma_f32_16x16x32_bf16(af[mr], bf, acc[mr][tt], 0, 0, 0);
    }
    __syncthreads();
  }

  #pragma unroll
  for (int mr = 0; mr < 2; ++mr)
    #pragma unroll
    for (int r = 0; r < 4; ++r) {
      int rr = row0 + wv * 32 + mr * 16 + kq * 4 + r;
      if (rr < N) {
        float s = dis[rr];
        #pragma unroll
        for (int t = 0; t < 8; ++t)
          C[(size_t)rr * 128 + t * 16 + m] = f2bf(acc[mr][t][r] * s);
      }
    }
}

// ---------------- small-K MFMA GEMM body (K=128) ----------------
template<int NT, int MR, bool AF32>
__device__ inline void mgemm_body(int bi, const void* __restrict__ Av,
                                  const unsigned short* __restrict__ WT,
                                  const float* __restrict__ dis, unsigned short* __restrict__ C,
                                  int ldc, int NOUT, int N) {
  constexpr int K = 128;
  const int tid = threadIdx.x;
  const int lane = tid & 63;
  const int wv = tid >> 6;
  const int m = lane & 15;
  const int kq = lane >> 4;
  const int orow = bi * (64 * MR) + wv * (16 * MR);

  int rowc[MR];
  #pragma unroll
  for (int mr = 0; mr < MR; ++mr) {
    int row = orow + mr * 16 + m;
    rowc[mr] = row < N ? row : N - 1;
  }

  f32x4 acc[MR][NT];
  #pragma unroll
  for (int mr = 0; mr < MR; ++mr)
    #pragma unroll
    for (int t = 0; t < NT; ++t) acc[mr][t] = {0.f, 0.f, 0.f, 0.f};

  #pragma unroll 4
  for (int k0 = 0; k0 < K; k0 += 32) {
    bf16x8 af[MR];
    #pragma unroll
    for (int mr = 0; mr < MR; ++mr) {
      if constexpr (AF32) {
        const float* Arow = (const float*)Av + (size_t)rowc[mr] * K + kq * 8 + k0;
        float4 a0 = *(const float4*)Arow;
        float4 a1 = *(const float4*)(Arow + 4);
        af[mr][0] = (short)f2bf(a0.x); af[mr][1] = (short)f2bf(a0.y);
        af[mr][2] = (short)f2bf(a0.z); af[mr][3] = (short)f2bf(a0.w);
        af[mr][4] = (short)f2bf(a1.x); af[mr][5] = (short)f2bf(a1.y);
        af[mr][6] = (short)f2bf(a1.z); af[mr][7] = (short)f2bf(a1.w);
      } else {
        const unsigned short* Arow = (const unsigned short*)Av + (size_t)rowc[mr] * K + kq * 8 + k0;
        af[mr] = *(const bf16x8*)Arow;
      }
    }
    bf16x8 bf[NT];
    #pragma unroll
    for (int t = 0; t < NT; ++t)
      bf[t] = *(const bf16x8*)(WT + (size_t)(t * 16 + m) * K + k0 + kq * 8);
    #pragma unroll
    for (int t = 0; t < NT; ++t)
      #pragma unroll
      for (int mr = 0; mr < MR; ++mr)
        acc[mr][t] = __builtin_amdgcn_mfma_f32_16x16x32_bf16(af[mr], bf[t], acc[mr][t], 0, 0, 0);
  }
  #pragma unroll
  for (int mr = 0; mr < MR; ++mr) {
    #pragma unroll
    for (int r = 0; r < 4; ++r) {
      int rr = orow + mr * 16 + kq * 4 + r;
      if (rr < N) {
        float s = dis ? dis[rr] : 1.f;
        #pragma unroll
        for (int t = 0; t < NT; ++t) {
          int cc = t * 16 + m;
          if (cc < NOUT)
            C[(size_t)rr * ldc + cc] = f2bf(acc[mr][t][r] * s);
        }
      }
    }
  }
}

// conv2 GEMM (A=G bf16) + spectral GEMM (A=eig fp32) in one launch; outputs disjoint (F, XP)
__global__ __launch_bounds__(256)
void k_mgemm2x(const unsigned short* __restrict__ G, const unsigned short* __restrict__ WT2,
               const float* __restrict__ dis, unsigned short* __restrict__ F,
               const float* __restrict__ eig, const unsigned short* __restrict__ WTl,
               unsigned short* __restrict__ XP, int N, int nA) {
  if ((int)blockIdx.x < nA)
    mgemm_body<4, 2, false>(blockIdx.x, G, WT2, dis, F, 64, 64, N);
  else
    mgemm_body<4, 2, true>(blockIdx.x - nA, eig, WTl, nullptr, XP, 64, 64, N);
}

// conv3 GEMM: A = [H2 | XP] (both [N][64] bf16), NOUT=40
__global__ __launch_bounds__(256)
void k_mgemm3(const unsigned short* __restrict__ H2, const unsigned short* __restrict__ XP,
              const unsigned short* __restrict__ WT3, const float* __restrict__ dis,
              unsigned short* __restrict__ C, int N) {
  constexpr int NT = 3, MR = 2;
  const int tid = threadIdx.x;
  const int lane = tid & 63;
  const int wv = tid >> 6;
  const int m = lane & 15;
  const int kq = lane >> 4;
  const int orow = blockIdx.x * (64 * MR) + wv * (16 * MR);

  int rowc[MR];
  #pragma unroll
  for (int mr = 0; mr < MR; ++mr) {
    int row = orow + mr * 16 + m;
    rowc[mr] = row < N ? row : N - 1;
  }

  f32x4 acc[MR][NT];
  #pragma unroll
  for (int mr = 0; mr < MR; ++mr)
    #pragma unroll
    for (int t = 0; t < NT; ++t) acc[mr][t] = {0.f, 0.f, 0.f, 0.f};

  #pragma unroll 4
  for (int k0 = 0; k0 < 128; k0 += 32) {
    const unsigned short* Abase = (k0 < 64) ? H2 : XP;
    const int kk = (k0 & 63) + kq * 8;
    bf16x8 af[MR];
    #pragma unroll
    for (int mr = 0; mr < MR; ++mr)
      af[mr] = *(const bf16x8*)(Abase + (size_t)rowc[mr] * 64 + kk);
    bf16x8 bf[NT];
    #pragma unroll
    for (int t = 0; t < NT; ++t)
      bf[t] = *(const bf16x8*)(WT3 + (size_t)(t * 16 + m) * 128 + k0 + kq * 8);
    #pragma unroll
    for (int t = 0; t < NT; ++t)
      #pragma unroll
      for (int mr = 0; mr < MR; ++mr)
        acc[mr][t] = __builtin_amdgcn_mfma_f32_16x16x32_bf16(af[mr], bf[t], acc[mr][t], 0, 0, 0);
  }
  #pragma unroll
  for (int mr = 0; mr < MR; ++mr) {
    #pragma unroll
    for (int r = 0; r < 4; ++r) {
      int rr = orow + mr * 16 + kq * 4 + r;
      if (rr < N) {
        float s = dis[rr];
        #pragma unroll
        for (int t = 0; t < NT; ++t) {
          int cc = t * 16 + m;
          if (cc < 40)
            C[(size_t)rr * 40 + cc] = f2bf(acc[mr][t][r] * s);
        }
      }
    }
  }
}

// ---------------- aggregation: 32 lanes per row, 2 edges per load ----------------
template<int D, bool RELU>
__launch_bounds__(BLK)
__global__ void k_agg2(const unsigned short* __restrict__ g, int ldg,
                       const float* __restrict__ dis, const float* __restrict__ bias,
                       const int* __restrict__ offs, const int* __restrict__ csr,
                       unsigned short* __restrict__ dst, int ldd, int N) {
  constexpr int CPL = D / 32;                 // cols per lane: 4 (D=128) or 2 (D=64)
  int wid = (blockIdx.x * BLK + threadIdx.x) >> 6;
  int lane = threadIdx.x & 63;
  if (wid >= N) return;
  const int l5 = lane >> 5, c = lane & 31;
  float acc[CPL];
  #pragma unroll
  for (int k = 0; k < CPL; ++k) acc[k] = 0.f;

  auto addrow = [&](int r) {
    if constexpr (CPL == 4) {
      uint2 w = *(const uint2*)&g[(size_t)r * ldg + c * 4];
      acc[0] += bf2f_lo(w.x); acc[1] += bf2f_hi(w.x);
      acc[2] += bf2f_lo(w.y); acc[3] += bf2f_hi(w.y);
    } else {
      unsigned int w = *(const unsigned int*)&g[(size_t)r * ldg + c * 2];
      acc[0] += bf2f_lo(w); acc[1] += bf2f_hi(w);
    }
  };

  if (l5 == 0) addrow(wid);                   // self row, counted once
  int beg = offs[wid], end = offs[wid + 1];
  for (int e0 = beg; e0 < end; e0 += 64) {
    int cnt = end - e0; if (cnt > 64) cnt = 64;
    int u = (lane < cnt) ? csr[e0 + lane] : 0;
    int j = 0;
    for (; j + 3 < cnt; j += 4) {
      int r0 = __shfl(u, j + l5);
      int r1 = __shfl(u, j + 2 + l5);
      addrow(r0); addrow(r1);
    }
    for (; j < cnt; j += 2) {
      int jj = j + l5;
      int r0 = __shfl(u, jj < cnt ? jj : j);
      if (jj < cnt) addrow(r0);
    }
  }
  #pragma unroll
  for (int k = 0; k < CPL; ++k) acc[k] += __shfl_xor(acc[k], 32);

  if (l5 == 0) {
    float dv = dis[wid];
    float o[CPL];
    #pragma unroll
    for (int k = 0; k < CPL; ++k) {
      o[k] = dv * acc[k] + bias[c * CPL + k];
      if constexpr (RELU) o[k] = fmaxf(o[k], 0.f);
    }
    if constexpr (CPL == 4) {
      uint2 pw;
      pw.x = (unsigned)f2bf(o[0]) | ((unsigned)f2bf(o[1]) << 16);
      pw.y = (unsigned)f2bf(o[2]) | ((unsigned)f2bf(o[3]) << 16);
      *(uint2*)&dst[(size_t)wid * ldd + c * 4] = pw;
    } else {
      unsigned int pw = (unsigned)f2bf(o[0]) | ((unsigned)f2bf(o[1]) << 16);
      *(unsigned int*)&dst[(size_t)wid * ldd + c * 2] = pw;
    }
  }
}

// ---------------- aggregation D=40 + log_softmax, fp32 out ----------------
__launch_bounds__(BLK)
__global__ void k_agg40(const unsigned short* __restrict__ g,
                        const float* __restrict__ dis, const float* __restrict__ bias,
                        const int* __restrict__ offs, const int* __restrict__ csr,
                        float* __restrict__ dst, int N) {
  int wid = (blockIdx.x * BLK + threadIdx.x) >> 6;
  int lane = threadIdx.x & 63;
  if (wid >= N) return;
  const int l5 = lane >> 5, c = lane & 31;
  const bool act = c < 20;
  float a0 = 0.f, a1 = 0.f;
  auto addrow = [&](int r) {
    if (act) {
      unsigned int w = *(const unsigned int*)&g[(size_t)r * 40 + c * 2];
      a0 += bf2f_lo(w); a1 += bf2f_hi(w);
    }
  };
  if (l5 == 0) addrow(wid);
  int beg = offs[wid], end = offs[wid + 1];
  for (int e0 = beg; e0 < end; e0 += 64) {
    int cnt = end - e0; if (cnt > 64) cnt = 64;
    int u = (lane < cnt) ? csr[e0 + lane] : 0;
    int j = 0;
    for (; j + 3 < cnt; j += 4) {
      int r0 = __shfl(u, j + l5);
      int r1 = __shfl(u, j + 2 + l5);
      addrow(r0); addrow(r1);
    }
    for (; j < cnt; j += 2) {
      int jj = j + l5;
      int r0 = __shfl(u, jj < cnt ? jj : j);
      if (jj < cnt) addrow(r0);
    }
  }
  a0 += __shfl_xor(a0, 32);
  a1 += __shfl_xor(a1, 32);

  if (l5 == 0) {
    float dv = dis[wid];
    float o0 = act ? dv * a0 + bias[c * 2]     : -__builtin_inff();
    float o1 = act ? dv * a1 + bias[c * 2 + 1] : -__builtin_inff();
    float mx = fmaxf(o0, o1);
    #pragma unroll
    for (int s = 16; s >= 1; s >>= 1) mx = fmaxf(mx, __shfl_down(mx, s, 32));
    mx = __shfl(mx, 0, 32);
    float ex = act ? (expf(o0 - mx) + expf(o1 - mx)) : 0.f;
    #pragma unroll
    for (int s = 16; s >= 1; s >>= 1) ex += __shfl_down(ex, s, 32);
    float ls = logf(__shfl(ex, 0, 32));
    if (act) {
      float2 r = make_float2(o0 - mx - ls, o1 - mx - ls);
      *(float2*)&dst[(size_t)wid * 40 + c * 2] = r;
    }
  }
}

// ---------------- launcher ----------------
extern "C" void kernel_launch(void* const* d_in, const int* in_sizes, int n_in,
                              void* d_out, int out_size, void* d_ws, size_t ws_size,
                              hipStream_t stream) {
  const float* x    = (const float*)d_in[0];
  const int*   ei   = (const int*)d_in[1];
  const float* eig  = (const float*)d_in[2];
  const float* W1   = (const float*)d_in[3];
  const float* b1   = (const float*)d_in[4];
  const float* W2   = (const float*)d_in[5];
  const float* b2   = (const float*)d_in[6];
  const float* linW = (const float*)d_in[7];
  const float* W3   = (const float*)d_in[8];
  const float* b3   = (const float*)d_in[9];
  float* out = (float*)d_out;

  const int N = in_sizes[0] / 512;
  const int E = in_sizes[1] / 2;

  char* ws = (char*)d_ws;
  size_t off = 0;
  auto alloc = [&](size_t bytes) { char* p = ws + off; off = ws_align(off + bytes); return p; };
  unsigned int* pk = (unsigned int*)alloc((size_t)E * 4);   // packed (col<<16)|row
  unsigned int* P  = (unsigned int*)alloc((size_t)E * 4);   // window-partitioned edges
  int*   csr    = (int*)alloc((size_t)E * 4);
  int*   offs   = (int*)alloc((size_t)(N + 1) * 4);
  int*   cnt    = (int*)alloc((size_t)NB * 256 * 4);
  int*   base   = (int*)alloc((size_t)NB * 256 * 4);
  int*   woffs  = (int*)alloc(257 * 4);
  float* dis    = (float*)alloc((size_t)N * 4);
  unsigned short* F  = (unsigned short*)alloc((size_t)N * 128 * 2);  // conv GEMM outputs
  unsigned short* G  = (unsigned short*)alloc((size_t)N * 128 * 2);  // h1
  unsigned short* XP = (unsigned short*)alloc((size_t)N * 64 * 2);   // spectral xp
  unsigned short* H2 = (unsigned short*)alloc((size_t)N * 64 * 2);   // conv2 output
  unsigned short* WT1 = (unsigned short*)alloc(128 * 512 * 2);
  unsigned short* WT2 = (unsigned short*)alloc(64 * 128 * 2);
  unsigned short* WTl = (unsigned short*)alloc(64 * 128 * 2);
  unsigned short* WT3 = (unsigned short*)alloc(48 * 128 * 2);

  const int nChunk = (E + NB - 1) / NB;
  const int NW = (N + 255) / 256;           // 256-node windows
  const int WTB = (88064 + BLK - 1) / BLK;  // wt tail blocks

  k_pack_wt<<<NB + WTB, BLK, 0, stream>>>(ei, pk, cnt, E, nChunk,
                                          W1, W2, linW, W3, WT1, WT2, WTl, WT3);
  k_wscan<<<1, 256, 0, stream>>>(cnt, woffs, base, NB, E);
  k_part_scatter<<<NB, BLK, 0, stream>>>(pk, base, P, E, nChunk);
  k_window_build<<<NW, BLK, 0, stream>>>(P, woffs, dis, offs, csr, N, E);

  const int gG1 = (N + 127) / 128;    // 128 rows/block
  const int gA = (N + 3) / 4;         // agg blocks (4 waves/block)

  // conv1: g1 = (x @ W1)*dis ; h1 = relu(dis*(g1[v]+sum) + b1)   [h1 -> G]
  k_gemm1<<<gG1, BLK, 0, stream>>>(x, WT1, dis, F, N);
  k_agg2<128, true><<<gA, BLK, 0, stream>>>(F, 128, dis, b1, offs, csr, G, 128, N);
  // conv2 GEMM (G->F 64 cols) + spectral (eig->XP) in one launch
  k_mgemm2x<<<2 * gG1, BLK, 0, stream>>>(G, WT2, dis, F, eig, WTl, XP, N, gG1);
  k_agg2<64, true><<<gA, BLK, 0, stream>>>(F, 64, dis, b2, offs, csr, H2, 64, N);
  // conv3: g3 = ([H2|XP] @ W3)*dis ; out = log_softmax(dis*(g3[v]+sum)+b3)
  k_mgemm3<<<gG1, BLK, 0, stream>>>(H2, XP, WT3, dis, F, N);
  k_agg40<<<gA, BLK, 0, stream>>>(F, dis, b3, offs, csr, out, N);
}

// Round 11
// 286.016 us; speedup vs baseline: 1.4369x; 1.0258x over previous
//
#include <hip/hip_runtime.h>
#include <cstdint>
#include <cstddef>

constexpr int BLK = 256;
constexpr int NB = 128;          // partition blocks

static inline size_t ws_align(size_t x) { return (x + 255) & ~size_t(255); }

typedef __attribute__((ext_vector_type(8))) short bf16x8;
typedef __attribute__((ext_vector_type(4))) float f32x4;

__device__ inline unsigned short f2bf(float f) {
  unsigned int u = __float_as_uint(f);
  unsigned int r = (u + 0x7fffu + ((u >> 16) & 1u)) >> 16;   // RNE
  return (unsigned short)r;
}
__device__ inline float bf2f(unsigned short u) {
  return __uint_as_float(((unsigned int)u) << 16);
}
__device__ inline float bf2f_lo(unsigned int w) {
  return __uint_as_float(w << 16);
}
__device__ inline float bf2f_hi(unsigned int w) {
  return __uint_as_float(w & 0xffff0000u);
}

// async global->LDS, 16B per lane; lds dest wave-uniform base (+lane*16 implicit)
__device__ inline void gload16(const void* gp, void* lp) {
  __builtin_amdgcn_global_load_lds(
      (const __attribute__((address_space(1))) void*)gp,
      (__attribute__((address_space(3))) void*)lp, 16, 0, 0);
}

// ---------------- pack (+inline layout detect) + per-block window histogram + wt tail ----------------
__global__ void k_pack_wt(const int* __restrict__ ei, unsigned int* __restrict__ pk,
                          int* __restrict__ cnt, int E, int nChunk,
                          const float* __restrict__ W1, const float* __restrict__ W2,
                          const float* __restrict__ linW, const float* __restrict__ W3,
                          unsigned short* __restrict__ WT1, unsigned short* __restrict__ WT2,
                          unsigned short* __restrict__ WTl, unsigned short* __restrict__ WT3) {
  if (blockIdx.x >= NB) {
    int i = (blockIdx.x - NB) * BLK + threadIdx.x;   // flat wt index
    if (i < 65536) {                 // WT1: K=512, NOUT=128
      int n = i >> 9, k = i & 511;
      WT1[i] = f2bf(W1[(size_t)k * 128 + n]);
    } else if (i < 73728) {          // WT2: K=128, NOUT=64
      int j = i - 65536; int n = j >> 7, k = j & 127;
      WT2[j] = f2bf(W2[(size_t)k * 64 + n]);
    } else if (i < 81920) {          // WTl
      int j = i - 73728; int n = j >> 7, k = j & 127;
      WTl[j] = f2bf(linW[(size_t)k * 64 + n]);
    } else if (i < 88064) {          // WT3: K=128, NOUT=40, padded to 48
      int j = i - 81920; int n = j >> 7, k = j & 127;
      WT3[j] = f2bf(n < 40 ? W3[(size_t)k * 40 + n] : 0.f);
    }
    return;
  }
  __shared__ int hist[256];
  for (int t = threadIdx.x; t < 256; t += BLK) hist[t] = 0;
  __syncthreads();
  int allz = 1;
  #pragma unroll 8
  for (int i = 0; i < 32; ++i) allz &= (ei[2 * i + 1] == 0) ? 1 : 0;
  const bool i64 = allz != 0;
  int beg = blockIdx.x * nChunk, end = min(beg + nChunk, E);
  for (int i = beg + threadIdx.x; i < end; i += BLK) {
    int row, col;
    if (i64) { row = ei[2 * i]; col = ei[2 * (E + i)]; }
    else     { row = ei[i];     col = ei[E + i]; }
    unsigned int p = ((unsigned int)col << 16) | (unsigned int)row;
    pk[i] = p;
    atomicAdd(&hist[col >> 8], 1);
  }
  __syncthreads();
  for (int t = threadIdx.x; t < 256; t += BLK) cnt[blockIdx.x * 256 + t] = hist[t];
}

// ---------------- window scan: woffs + per-(block,window) bases ----------------
__global__ void k_wscan(const int* __restrict__ cnt, int* __restrict__ woffs,
                        int* __restrict__ base, int nb, int E) {
  __shared__ int wsums[5];
  int w = threadIdx.x;
  int s = 0;
  for (int b = 0; b < nb; ++b) s += cnt[b * 256 + w];
  int lane = w & 63, wv = w >> 6;
  int x = s;
  #pragma unroll
  for (int sh = 1; sh < 64; sh <<= 1) { int t = __shfl_up(x, sh); if (lane >= sh) x += t; }
  if (lane == 63) wsums[wv] = x;
  __syncthreads();
  if (w == 0) { int a = 0; for (int k = 0; k < 4; ++k) { int t = wsums[k]; wsums[k] = a; a += t; } }
  __syncthreads();
  int excl = x - s + wsums[wv];
  woffs[w] = excl;
  if (w == 255) woffs[256] = excl + s;   // == E
  int start = excl;
  for (int b = 0; b < nb; ++b) { base[b * 256 + w] = start; start += cnt[b * 256 + w]; }
}

// ---------------- merged: partition scatter (blocks [0,NB)) + GEMM1 (blocks [NB,..)) ----------------
// GEMM1 is UNSCALED: F = x @ W1 (bf16). dis applied at gather time in k_agg2<GDIS=true>.
__global__ __launch_bounds__(256)
void k_part_gemm1(const unsigned int* __restrict__ pk, const int* __restrict__ base,
                  unsigned int* __restrict__ P, int E, int nChunk,
                  const float* __restrict__ x, const unsigned short* __restrict__ WT,
                  unsigned short* __restrict__ C, int N) {
  __shared__ __align__(16) char smem[49152];
  if (blockIdx.x < NB) {
    // ---- partition scatter ----
    int* cur = (int*)smem;
    for (int t = threadIdx.x; t < 256; t += BLK) cur[t] = base[blockIdx.x * 256 + t];
    __syncthreads();
    int beg = blockIdx.x * nChunk, end = min(beg + nChunk, E);
    for (int i = beg + threadIdx.x; i < end; i += BLK) {
      unsigned int p = pk[i];
      int pos = atomicAdd(&cur[p >> 24], 1);
      P[pos] = p;
    }
    return;
  }
  // ---- GEMM1: K=512, NOUT=128, double-buffered global_load_lds ----
  float* As0 = (float*)smem;                                   // [2][128*32]
  unsigned short* Wsl0 = (unsigned short*)(smem + 32768);      // [2][4096]
  const int tid = threadIdx.x;
  const int lane = tid & 63, wv = tid >> 6;
  const int m = lane & 15, kq = lane >> 4;
  const int row0 = ((int)blockIdx.x - NB) * 128;

  const int r8 = lane >> 3;           // A: row within 8-row issue
  const int c8 = lane & 7;            // A: 16B slot within 128B row
  int agrow[4];
  #pragma unroll
  for (int jj = 0; jj < 4; ++jj) {
    int gr = row0 + wv * 32 + jj * 8 + r8;
    agrow[jj] = gr < N ? gr : N - 1;
  }

  f32x4 acc[2][8];
  #pragma unroll
  for (int mr = 0; mr < 2; ++mr)
    #pragma unroll
    for (int t = 0; t < 8; ++t) acc[mr][t] = {0.f, 0.f, 0.f, 0.f};

  auto STAGE = [&](int pb, int kb) {
    #pragma unroll
    for (int jj = 0; jj < 4; ++jj) {
      const float* src = x + (size_t)agrow[jj] * 512 + kb * 32 + (c8 ^ r8) * 4;
      gload16(src, As0 + pb * 4096 + (wv * 32 + jj * 8) * 32);
    }
    #pragma unroll
    for (int jj = 0; jj < 2; ++jj) {
      int issue = wv * 2 + jj;
      int slot = issue >> 1, half = issue & 1;
      const unsigned short* src = WT + (size_t)(half * 64 + lane) * 512 + kb * 32 + slot * 8;
      gload16(src, Wsl0 + pb * 4096 + slot * 1024 + half * 512);
    }
  };

  STAGE(0, 0);
  __syncthreads();

  #pragma unroll 1
  for (int t = 0; t < 16; ++t) {
    const int p = t & 1;
    if (t < 15) STAGE(p ^ 1, t + 1);

    const char* Ab = (const char*)(As0 + p * 4096);
    const char* Wb = (const char*)(Wsl0 + p * 4096);
    bf16x8 af[2];
    #pragma unroll
    for (int mr = 0; mr < 2; ++mr) {
      int row = wv * 32 + mr * 16 + m;
      int s = row & 7;
      f32x4 lo = *(const f32x4*)(Ab + row * 128 + ((kq * 2) ^ s) * 16);
      f32x4 hi = *(const f32x4*)(Ab + row * 128 + ((kq * 2 + 1) ^ s) * 16);
      af[mr][0] = (short)f2bf(lo[0]); af[mr][1] = (short)f2bf(lo[1]);
      af[mr][2] = (short)f2bf(lo[2]); af[mr][3] = (short)f2bf(lo[3]);
      af[mr][4] = (short)f2bf(hi[0]); af[mr][5] = (short)f2bf(hi[1]);
      af[mr][6] = (short)f2bf(hi[2]); af[mr][7] = (short)f2bf(hi[3]);
    }
    #pragma unroll
    for (int tt = 0; tt < 8; ++tt) {
      bf16x8 bf = *(const bf16x8*)(Wb + kq * 2048 + (tt * 16 + m) * 16);
      #pragma unroll
      for (int mr = 0; mr < 2; ++mr)
        acc[mr][tt] = __builtin_amdgcn_mfma_f32_16x16x32_bf16(af[mr], bf, acc[mr][tt], 0, 0, 0);
    }
    __syncthreads();
  }

  #pragma unroll
  for (int mr = 0; mr < 2; ++mr)
    #pragma unroll
    for (int r = 0; r < 4; ++r) {
      int rr = row0 + wv * 32 + mr * 16 + kq * 4 + r;
      if (rr < N) {
        #pragma unroll
        for (int t = 0; t < 8; ++t)
          C[(size_t)rr * 128 + t * 16 + m] = f2bf(acc[mr][t][r]);
      }
    }
}

// ---------------- per-window build: deg -> dis, offs, csr ----------------
__global__ void k_window_build(const unsigned int* __restrict__ P,
                               const int* __restrict__ woffs,
                               float* __restrict__ dis, int* __restrict__ offs,
                               int* __restrict__ csr, int N, int E) {
  __shared__ int hist[256];
  __shared__ int wsums[5];
  __shared__ int lbase[256];
  const int node0 = blockIdx.x * 256;
  const int t = threadIdx.x;
  hist[t] = 0;
  __syncthreads();
  const int beg = woffs[blockIdx.x], end = woffs[blockIdx.x + 1];
  for (int i = beg + t; i < end; i += BLK)
    atomicAdd(&hist[(P[i] >> 16) & 255], 1);
  __syncthreads();
  const int dg = hist[t];
  if (node0 + t < N) dis[node0 + t] = 1.0f / sqrtf((float)(dg + 1));
  int lane = t & 63, wv = t >> 6;
  int x = dg;
  #pragma unroll
  for (int sh = 1; sh < 64; sh <<= 1) { int q = __shfl_up(x, sh); if (lane >= sh) x += q; }
  if (lane == 63) wsums[wv] = x;
  __syncthreads();
  if (t == 0) { int a = 0; for (int k = 0; k < 4; ++k) { int q = wsums[k]; wsums[k] = a; a += q; } }
  __syncthreads();
  const int goff = beg + (x - dg + wsums[wv]);
  if (node0 + t < N) offs[node0 + t] = goff;
  lbase[t] = goff;
  __syncthreads();
  for (int i = beg + t; i < end; i += BLK) {
    unsigned int p = P[i];
    int pos = atomicAdd(&lbase[(p >> 16) & 255], 1);
    csr[pos] = (int)(p & 0xffffu);
  }
  if (blockIdx.x == 0 && t == 0) offs[N] = E;
}

// ---------------- small-K MFMA GEMM body (K=128) ----------------
template<int NT, int MR, bool AF32>
__device__ inline void mgemm_body(int bi, const void* __restrict__ Av,
                                  const unsigned short* __restrict__ WT,
                                  const float* __restrict__ dis, unsigned short* __restrict__ C,
                                  int ldc, int NOUT, int N) {
  constexpr int K = 128;
  const int tid = threadIdx.x;
  const int lane = tid & 63;
  const int wv = tid >> 6;
  const int m = lane & 15;
  const int kq = lane >> 4;
  const int orow = bi * (64 * MR) + wv * (16 * MR);

  int rowc[MR];
  #pragma unroll
  for (int mr = 0; mr < MR; ++mr) {
    int row = orow + mr * 16 + m;
    rowc[mr] = row < N ? row : N - 1;
  }

  f32x4 acc[MR][NT];
  #pragma unroll
  for (int mr = 0; mr < MR; ++mr)
    #pragma unroll
    for (int t = 0; t < NT; ++t) acc[mr][t] = {0.f, 0.f, 0.f, 0.f};

  #pragma unroll 4
  for (int k0 = 0; k0 < K; k0 += 32) {
    bf16x8 af[MR];
    #pragma unroll
    for (int mr = 0; mr < MR; ++mr) {
      if constexpr (AF32) {
        const float* Arow = (const float*)Av + (size_t)rowc[mr] * K + kq * 8 + k0;
        float4 a0 = *(const float4*)Arow;
        float4 a1 = *(const float4*)(Arow + 4);
        af[mr][0] = (short)f2bf(a0.x); af[mr][1] = (short)f2bf(a0.y);
        af[mr][2] = (short)f2bf(a0.z); af[mr][3] = (short)f2bf(a0.w);
        af[mr][4] = (short)f2bf(a1.x); af[mr][5] = (short)f2bf(a1.y);
        af[mr][6] = (short)f2bf(a1.z); af[mr][7] = (short)f2bf(a1.w);
      } else {
        const unsigned short* Arow = (const unsigned short*)Av + (size_t)rowc[mr] * K + kq * 8 + k0;
        af[mr] = *(const bf16x8*)Arow;
      }
    }
    bf16x8 bf[NT];
    #pragma unroll
    for (int t = 0; t < NT; ++t)
      bf[t] = *(const bf16x8*)(WT + (size_t)(t * 16 + m) * K + k0 + kq * 8);
    #pragma unroll
    for (int t = 0; t < NT; ++t)
      #pragma unroll
      for (int mr = 0; mr < MR; ++mr)
        acc[mr][t] = __builtin_amdgcn_mfma_f32_16x16x32_bf16(af[mr], bf[t], acc[mr][t], 0, 0, 0);
  }
  #pragma unroll
  for (int mr = 0; mr < MR; ++mr) {
    #pragma unroll
    for (int r = 0; r < 4; ++r) {
      int rr = orow + mr * 16 + kq * 4 + r;
      if (rr < N) {
        float s = dis ? dis[rr] : 1.f;
        #pragma unroll
        for (int t = 0; t < NT; ++t) {
          int cc = t * 16 + m;
          if (cc < NOUT)
            C[(size_t)rr * ldc + cc] = f2bf(acc[mr][t][r] * s);
        }
      }
    }
  }
}

// conv2 GEMM (A=G bf16) + spectral GEMM (A=eig fp32) in one launch; outputs disjoint (F, XP)
__global__ __launch_bounds__(256)
void k_mgemm2x(const unsigned short* __restrict__ G, const unsigned short* __restrict__ WT2,
               const float* __restrict__ dis, unsigned short* __restrict__ F,
               const float* __restrict__ eig, const unsigned short* __restrict__ WTl,
               unsigned short* __restrict__ XP, int N, int nA) {
  if ((int)blockIdx.x < nA)
    mgemm_body<4, 2, false>(blockIdx.x, G, WT2, dis, F, 64, 64, N);
  else
    mgemm_body<4, 2, true>(blockIdx.x - nA, eig, WTl, nullptr, XP, 64, 64, N);
}

// conv3 GEMM: A = [H2 | XP] (both [N][64] bf16), NOUT=40
__global__ __launch_bounds__(256)
void k_mgemm3(const unsigned short* __restrict__ H2, const unsigned short* __restrict__ XP,
              const unsigned short* __restrict__ WT3, const float* __restrict__ dis,
              unsigned short* __restrict__ C, int N) {
  constexpr int NT = 3, MR = 2;
  const int tid = threadIdx.x;
  const int lane = tid & 63;
  const int wv = tid >> 6;
  const int m = lane & 15;
  const int kq = lane >> 4;
  const int orow = blockIdx.x * (64 * MR) + wv * (16 * MR);

  int rowc[MR];
  #pragma unroll
  for (int mr = 0; mr < MR; ++mr) {
    int row = orow + mr * 16 + m;
    rowc[mr] = row < N ? row : N - 1;
  }

  f32x4 acc[MR][NT];
  #pragma unroll
  for (int mr = 0; mr < MR; ++mr)
    #pragma unroll
    for (int t = 0; t < NT; ++t) acc[mr][t] = {0.f, 0.f, 0.f, 0.f};

  #pragma unroll 4
  for (int k0 = 0; k0 < 128; k0 += 32) {
    const unsigned short* Abase = (k0 < 64) ? H2 : XP;
    const int kk = (k0 & 63) + kq * 8;
    bf16x8 af[MR];
    #pragma unroll
    for (int mr = 0; mr < MR; ++mr)
      af[mr] = *(const bf16x8*)(Abase + (size_t)rowc[mr] * 64 + kk);
    bf16x8 bf[NT];
    #pragma unroll
    for (int t = 0; t < NT; ++t)
      bf[t] = *(const bf16x8*)(WT3 + (size_t)(t * 16 + m) * 128 + k0 + kq * 8);
    #pragma unroll
    for (int t = 0; t < NT; ++t)
      #pragma unroll
      for (int mr = 0; mr < MR; ++mr)
        acc[mr][t] = __builtin_amdgcn_mfma_f32_16x16x32_bf16(af[mr], bf[t], acc[mr][t], 0, 0, 0);
  }
  #pragma unroll
  for (int mr = 0; mr < MR; ++mr) {
    #pragma unroll
    for (int r = 0; r < 4; ++r) {
      int rr = orow + mr * 16 + kq * 4 + r;
      if (rr < N) {
        float s = dis[rr];
        #pragma unroll
        for (int t = 0; t < NT; ++t) {
          int cc = t * 16 + m;
          if (cc < 40)
            C[(size_t)rr * 40 + cc] = f2bf(acc[mr][t][r] * s);
        }
      }
    }
  }
}

// ---------------- aggregation: 32 lanes per row, 2 edges per load ----------------
// GDIS: gather-side dis weighting (g unscaled; out[v]=dis[v]*(sum du*g[u] + dv*g[v])+b)
template<int D, bool RELU, bool GDIS>
__launch_bounds__(BLK)
__global__ void k_agg2(const unsigned short* __restrict__ g, int ldg,
                       const float* __restrict__ dis, const float* __restrict__ bias,
                       const int* __restrict__ offs, const int* __restrict__ csr,
                       unsigned short* __restrict__ dst, int ldd, int N) {
  constexpr int CPL = D / 32;                 // cols per lane: 4 (D=128) or 2 (D=64)
  int wid = (blockIdx.x * BLK + threadIdx.x) >> 6;
  int lane = threadIdx.x & 63;
  if (wid >= N) return;
  const int l5 = lane >> 5, c = lane & 31;
  const float dv = dis[wid];
  float acc[CPL];
  #pragma unroll
  for (int k = 0; k < CPL; ++k) acc[k] = 0.f;

  auto addrow = [&](int r, float w) {
    if constexpr (CPL == 4) {
      uint2 v = *(const uint2*)&g[(size_t)r * ldg + c * 4];
      acc[0] = fmaf(w, bf2f_lo(v.x), acc[0]); acc[1] = fmaf(w, bf2f_hi(v.x), acc[1]);
      acc[2] = fmaf(w, bf2f_lo(v.y), acc[2]); acc[3] = fmaf(w, bf2f_hi(v.y), acc[3]);
    } else {
      unsigned int v = *(const unsigned int*)&g[(size_t)r * ldg + c * 2];
      acc[0] = fmaf(w, bf2f_lo(v), acc[0]); acc[1] = fmaf(w, bf2f_hi(v), acc[1]);
    }
  };

  if (l5 == 0) addrow(wid, GDIS ? dv : 1.0f);   // self row, counted once
  int beg = offs[wid], end = offs[wid + 1];
  for (int e0 = beg; e0 < end; e0 += 64) {
    int cnt = end - e0; if (cnt > 64) cnt = 64;
    int u = (lane < cnt) ? csr[e0 + lane] : 0;
    float du = 1.0f;
    if constexpr (GDIS) du = (lane < cnt) ? dis[u] : 0.f;
    int j = 0;
    for (; j + 3 < cnt; j += 4) {
      int r0 = __shfl(u, j + l5);
      int r1 = __shfl(u, j + 2 + l5);
      float w0 = GDIS ? __shfl(du, j + l5) : 1.0f;
      float w1 = GDIS ? __shfl(du, j + 2 + l5) : 1.0f;
      addrow(r0, w0); addrow(r1, w1);
    }
    for (; j < cnt; j += 2) {
      int jj = j + l5;
      int si = jj < cnt ? jj : j;
      int r0 = __shfl(u, si);
      float w0 = GDIS ? __shfl(du, si) : 1.0f;
      if (jj < cnt) addrow(r0, w0);
    }
  }
  #pragma unroll
  for (int k = 0; k < CPL; ++k) acc[k] += __shfl_xor(acc[k], 32);

  if (l5 == 0) {
    float o[CPL];
    #pragma unroll
    for (int k = 0; k < CPL; ++k) {
      o[k] = dv * acc[k] + bias[c * CPL + k];
      if constexpr (RELU) o[k] = fmaxf(o[k], 0.f);
    }
    if constexpr (CPL == 4) {
      uint2 pw;
      pw.x = (unsigned)f2bf(o[0]) | ((unsigned)f2bf(o[1]) << 16);
      pw.y = (unsigned)f2bf(o[2]) | ((unsigned)f2bf(o[3]) << 16);
      *(uint2*)&dst[(size_t)wid * ldd + c * 4] = pw;
    } else {
      unsigned int pw = (unsigned)f2bf(o[0]) | ((unsigned)f2bf(o[1]) << 16);
      *(unsigned int*)&dst[(size_t)wid * ldd + c * 2] = pw;
    }
  }
}

// ---------------- aggregation D=40 + log_softmax, fp32 out ----------------
__launch_bounds__(BLK)
__global__ void k_agg40(const unsigned short* __restrict__ g,
                        const float* __restrict__ dis, const float* __restrict__ bias,
                        const int* __restrict__ offs, const int* __restrict__ csr,
                        float* __restrict__ dst, int N) {
  int wid = (blockIdx.x * BLK + threadIdx.x) >> 6;
  int lane = threadIdx.x & 63;
  if (wid >= N) return;
  const int l5 = lane >> 5, c = lane & 31;
  const bool act = c < 20;
  float a0 = 0.f, a1 = 0.f;
  auto addrow = [&](int r) {
    if (act) {
      unsigned int w = *(const unsigned int*)&g[(size_t)r * 40 + c * 2];
      a0 += bf2f_lo(w); a1 += bf2f_hi(w);
    }
  };
  if (l5 == 0) addrow(wid);
  int beg = offs[wid], end = offs[wid + 1];
  for (int e0 = beg; e0 < end; e0 += 64) {
    int cnt = end - e0; if (cnt > 64) cnt = 64;
    int u = (lane < cnt) ? csr[e0 + lane] : 0;
    int j = 0;
    for (; j + 3 < cnt; j += 4) {
      int r0 = __shfl(u, j + l5);
      int r1 = __shfl(u, j + 2 + l5);
      addrow(r0); addrow(r1);
    }
    for (; j < cnt; j += 2) {
      int jj = j + l5;
      int r0 = __shfl(u, jj < cnt ? jj : j);
      if (jj < cnt) addrow(r0);
    }
  }
  a0 += __shfl_xor(a0, 32);
  a1 += __shfl_xor(a1, 32);

  if (l5 == 0) {
    float dv = dis[wid];
    float o0 = act ? dv * a0 + bias[c * 2]     : -__builtin_inff();
    float o1 = act ? dv * a1 + bias[c * 2 + 1] : -__builtin_inff();
    float mx = fmaxf(o0, o1);
    #pragma unroll
    for (int s = 16; s >= 1; s >>= 1) mx = fmaxf(mx, __shfl_down(mx, s, 32));
    mx = __shfl(mx, 0, 32);
    float ex = act ? (expf(o0 - mx) + expf(o1 - mx)) : 0.f;
    #pragma unroll
    for (int s = 16; s >= 1; s >>= 1) ex += __shfl_down(ex, s, 32);
    float ls = logf(__shfl(ex, 0, 32));
    if (act) {
      float2 r = make_float2(o0 - mx - ls, o1 - mx - ls);
      *(float2*)&dst[(size_t)wid * 40 + c * 2] = r;
    }
  }
}

// ---------------- launcher ----------------
extern "C" void kernel_launch(void* const* d_in, const int* in_sizes, int n_in,
                              void* d_out, int out_size, void* d_ws, size_t ws_size,
                              hipStream_t stream) {
  const float* x    = (const float*)d_in[0];
  const int*   ei   = (const int*)d_in[1];
  const float* eig  = (const float*)d_in[2];
  const float* W1   = (const float*)d_in[3];
  const float* b1   = (const float*)d_in[4];
  const float* W2   = (const float*)d_in[5];
  const float* b2   = (const float*)d_in[6];
  const float* linW = (const float*)d_in[7];
  const float* W3   = (const float*)d_in[8];
  const float* b3   = (const float*)d_in[9];
  float* out = (float*)d_out;

  const int N = in_sizes[0] / 512;
  const int E = in_sizes[1] / 2;

  char* ws = (char*)d_ws;
  size_t off = 0;
  auto alloc = [&](size_t bytes) { char* p = ws + off; off = ws_align(off + bytes); return p; };
  unsigned int* pk = (unsigned int*)alloc((size_t)E * 4);   // packed (col<<16)|row
  unsigned int* P  = (unsigned int*)alloc((size_t)E * 4);   // window-partitioned edges
  int*   csr    = (int*)alloc((size_t)E * 4);
  int*   offs   = (int*)alloc((size_t)(N + 1) * 4);
  int*   cnt    = (int*)alloc((size_t)NB * 256 * 4);
  int*   base   = (int*)alloc((size_t)NB * 256 * 4);
  int*   woffs  = (int*)alloc(257 * 4);
  float* dis    = (float*)alloc((size_t)N * 4);
  unsigned short* F  = (unsigned short*)alloc((size_t)N * 128 * 2);  // conv GEMM outputs
  unsigned short* G  = (unsigned short*)alloc((size_t)N * 128 * 2);  // h1
  unsigned short* XP = (unsigned short*)alloc((size_t)N * 64 * 2);   // spectral xp
  unsigned short* H2 = (unsigned short*)alloc((size_t)N * 64 * 2);   // conv2 output
  unsigned short* WT1 = (unsigned short*)alloc(128 * 512 * 2);
  unsigned short* WT2 = (unsigned short*)alloc(64 * 128 * 2);
  unsigned short* WTl = (unsigned short*)alloc(64 * 128 * 2);
  unsigned short* WT3 = (unsigned short*)alloc(48 * 128 * 2);

  const int nChunk = (E + NB - 1) / NB;
  const int NW = (N + 255) / 256;           // 256-node windows
  const int WTB = (88064 + BLK - 1) / BLK;  // wt tail blocks
  const int gG1 = (N + 127) / 128;          // 128 rows/block
  const int gA = (N + 3) / 4;               // agg blocks (4 waves/block)

  k_pack_wt<<<NB + WTB, BLK, 0, stream>>>(ei, pk, cnt, E, nChunk,
                                          W1, W2, linW, W3, WT1, WT2, WTl, WT3);
  k_wscan<<<1, 256, 0, stream>>>(cnt, woffs, base, NB, E);
  // partition scatter runs concurrently with (unscaled) GEMM1
  k_part_gemm1<<<NB + gG1, BLK, 0, stream>>>(pk, base, P, E, nChunk, x, WT1, F, N);
  k_window_build<<<NW, BLK, 0, stream>>>(P, woffs, dis, offs, csr, N, E);

  // conv1 agg: h1 = relu(dis[v]*(sum du*g1[u] + dv*g1[v]) + b1)   [GDIS]
  k_agg2<128, true, true><<<gA, BLK, 0, stream>>>(F, 128, dis, b1, offs, csr, G, 128, N);
  // conv2 GEMM (G->F 64 cols, *dis) + spectral (eig->XP) in one launch
  k_mgemm2x<<<2 * gG1, BLK, 0, stream>>>(G, WT2, dis, F, eig, WTl, XP, N, gG1);
  k_agg2<64, true, false><<<gA, BLK, 0, stream>>>(F, 64, dis, b2, offs, csr, H2, 64, N);
  // conv3: g3 = ([H2|XP] @ W3)*dis ; out = log_softmax(dis*(g3[v]+sum)+b3)
  k_mgemm3<<<gG1, BLK, 0, stream>>>(H2, XP, WT3, dis, F, N);
  k_agg40<<<gA, BLK, 0, stream>>>(F, dis, b3, offs, csr, out, N);
}